// Round 1
// 456.102 us; speedup vs baseline: 1.0276x; 1.0276x over previous
//
#include <hip/hip_runtime.h>
#include <hip/hip_bf16.h>

#define H_    2048
#define NROWS 16384
#define HH    1024

typedef __bf16 bf16x8 __attribute__((ext_vector_type(8)));
typedef float  floatx4 __attribute__((ext_vector_type(4)));

__device__ __forceinline__ unsigned f2bf(float f) {
  unsigned u = __builtin_bit_cast(unsigned, f);
  u += 0x7fff + ((u >> 16) & 1);          // round-nearest-even to bf16
  return u >> 16;
}

__device__ __forceinline__ void gload_lds16(const void* g, void* l) {
  // 16B per lane, lands at wave-uniform LDS base + lane*16
  __builtin_amdgcn_global_load_lds(
      (const __attribute__((address_space(1))) unsigned*)g,
      (__attribute__((address_space(3))) unsigned*)l, 16, 0, 0);
}

// ---------------------------------------------------------------------------
// Kc: x fp32 -> xb bf16 (row-major, same layout). 8 elems/thread.
// ---------------------------------------------------------------------------
__global__ __launch_bounds__(256) void convert_x_kernel(
    const float* __restrict__ x, unsigned short* __restrict__ xb)
{
  size_t i = ((size_t)blockIdx.x * 256 + threadIdx.x) * 8;
  float4 v0 = *reinterpret_cast<const float4*>(x + i);
  float4 v1 = *reinterpret_cast<const float4*>(x + i + 4);
  uint4 o;
  o.x = f2bf(v0.x) | (f2bf(v0.y) << 16);
  o.y = f2bf(v0.z) | (f2bf(v0.w) << 16);
  o.z = f2bf(v1.x) | (f2bf(v1.y) << 16);
  o.w = f2bf(v1.z) | (f2bf(v1.w) << 16);
  *reinterpret_cast<uint4*>(xb + i) = o;
}

// ---------------------------------------------------------------------------
// Kt: W1 [k=2048][n=1024] fp32 -> W1t [n][k] bf16 via LDS tile transpose.
// ---------------------------------------------------------------------------
__global__ __launch_bounds__(256) void transpose_w1_kernel(
    const float* __restrict__ W1, unsigned short* __restrict__ W1t)
{
  __shared__ unsigned short tile[64][66];   // [k][n], pad 66 -> conflict-free col reads
  int k0 = blockIdx.x * 64;                 // 32
  int n0 = blockIdx.y * 64;                 // 16
  int t = threadIdx.x;
#pragma unroll
  for (int i = 0; i < 4; i++) {
    int idx = t + i * 256;
    int r = idx >> 4, c4 = (idx & 15) << 2;
    float4 v = *reinterpret_cast<const float4*>(W1 + (size_t)(k0 + r) * HH + n0 + c4);
    tile[r][c4 + 0] = (unsigned short)f2bf(v.x);
    tile[r][c4 + 1] = (unsigned short)f2bf(v.y);
    tile[r][c4 + 2] = (unsigned short)f2bf(v.z);
    tile[r][c4 + 3] = (unsigned short)f2bf(v.w);
  }
  __syncthreads();
#pragma unroll
  for (int i = 0; i < 2; i++) {
    int idx = t + i * 256;
    int n = idx >> 3, k8 = (idx & 7) << 3;
    uint4 o;
    o.x = (unsigned)tile[k8 + 0][n] | ((unsigned)tile[k8 + 1][n] << 16);
    o.y = (unsigned)tile[k8 + 2][n] | ((unsigned)tile[k8 + 3][n] << 16);
    o.z = (unsigned)tile[k8 + 4][n] | ((unsigned)tile[k8 + 5][n] << 16);
    o.w = (unsigned)tile[k8 + 6][n] | ((unsigned)tile[k8 + 7][n] << 16);
    *reinterpret_cast<uint4*>(W1t + (size_t)(n0 + n) * H_ + k0 + k8) = o;
  }
}

// ---------------------------------------------------------------------------
// K1 (fast): bf16 MFMA GEMM, 128x128 tile, BK=64, global_load_lds with
// both-sides XOR swizzle (conflict-free ds_read_b128), m-major grid for
// XCD L2 locality, fused relu(+b1)*W2 row-reduction epilogue -> s_pre.
// ---------------------------------------------------------------------------
__global__ __launch_bounds__(256) void gemm_v2_kernel(
    const unsigned short* __restrict__ xb, const unsigned short* __restrict__ W1t,
    const float* __restrict__ b1, const float* __restrict__ W2,
    float* __restrict__ s_pre)
{
  __shared__ unsigned short As[128 * 64];   // [m][k], chunk q stored at q^(row&7)
  __shared__ unsigned short Bs[128 * 64];   // [n][k], same swizzle

  const int t    = threadIdx.x;
  const int m0   = blockIdx.x * 128;  // m-major: linear id = m + 128*n, id%8 = m%8
  const int n0   = blockIdx.y * 128;  //  -> all 8 n-blocks of an m-panel share an XCD
  const int wave = t >> 6, lane = t & 63;
  const int wr   = (wave >> 1) * 64;
  const int wc   = (wave & 1) * 64;
  const int lcol = lane & 15, quad = lane >> 4;

  floatx4 acc[4][4] = {};

  // Staging: tile = 128 rows x 64 k = 1024 chunks of 16B; thread t stages
  // chunks {t, t+256, t+512, t+768}. chunk c -> row c>>3, pos c&7.
  // LDS dest is LINEAR (global_load_lds requirement); the XOR swizzle is
  // applied by permuting the per-lane GLOBAL source chunk: q = (c&7)^(row&7).
  // (row&7 is invariant across the +32-row calls, so sq is loop-invariant.)
  const int srow = t >> 3;
  const int sq   = (t & 7) ^ (srow & 7);
  const unsigned short* ag = xb  + (size_t)(m0 + srow) * H_ + sq * 8;
  const unsigned short* bg = W1t + (size_t)(n0 + srow) * H_ + sq * 8;
  unsigned short* al = As + 512 * wave;     // + lane*16B by HW
  unsigned short* bl = Bs + 512 * wave;

  for (int kk = 0; kk < H_; kk += 64) {
    __syncthreads();
#pragma unroll
    for (int j = 0; j < 4; j++) {
      gload_lds16(ag + kk + (size_t)(32 * j) * H_, al + 2048 * j);
      gload_lds16(bg + kk + (size_t)(32 * j) * H_, bl + 2048 * j);
    }
    __syncthreads();

#pragma unroll
    for (int h = 0; h < 2; h++) {           // two k=32 halves of the BK=64 tile
      bf16x8 af[4], bfr[4];
#pragma unroll
      for (int mt = 0; mt < 4; mt++) {
        int r = wr + mt * 16 + lcol;
        af[mt] = *reinterpret_cast<const bf16x8*>(
            As + r * 64 + ((((h << 2) | quad) ^ (r & 7)) << 3));
      }
#pragma unroll
      for (int nt = 0; nt < 4; nt++) {
        int r = wc + nt * 16 + lcol;
        bfr[nt] = *reinterpret_cast<const bf16x8*>(
            Bs + r * 64 + ((((h << 2) | quad) ^ (r & 7)) << 3));
      }
#pragma unroll
      for (int mt = 0; mt < 4; mt++)
#pragma unroll
        for (int nt = 0; nt < 4; nt++)
          acc[mt][nt] = __builtin_amdgcn_mfma_f32_16x16x32_bf16(af[mt], bfr[nt], acc[mt][nt], 0, 0, 0);
    }
  }

  // epilogue: relu(acc + b1[n]) * W2[n] summed over this block's 128 n-cols
  float rowsum[4][4];
#pragma unroll
  for (int mt = 0; mt < 4; mt++)
#pragma unroll
    for (int r = 0; r < 4; r++) rowsum[mt][r] = 0.f;

#pragma unroll
  for (int nt = 0; nt < 4; nt++) {
    int n = n0 + wc + nt * 16 + lcol;      // C/D col = lane&15
    float b1v = b1[n], w2v = W2[n];
#pragma unroll
    for (int mt = 0; mt < 4; mt++)
#pragma unroll
      for (int r = 0; r < 4; r++) {
        float h = fmaxf(acc[mt][nt][r] + b1v, 0.f);
        rowsum[mt][r] = fmaf(h, w2v, rowsum[mt][r]);
      }
  }
#pragma unroll
  for (int mt = 0; mt < 4; mt++)
#pragma unroll
    for (int r = 0; r < 4; r++) {
      float s = rowsum[mt][r];
      s += __shfl_xor(s, 1); s += __shfl_xor(s, 2);
      s += __shfl_xor(s, 4); s += __shfl_xor(s, 8);
      if (lcol == 0)
        atomicAdd(&s_pre[m0 + wr + mt * 16 + quad * 4 + r], s);  // C/D row = quad*4+r
    }
}

// ---------------------------------------------------------------------------
// K1 (fallback, small ws): round-1 fused GEMM with in-loop conversion.
// ---------------------------------------------------------------------------
__global__ __launch_bounds__(256) void gemm_score_kernel(
    const float* __restrict__ x, const float* __restrict__ W1,
    const float* __restrict__ b1, const float* __restrict__ W2,
    float* __restrict__ s_pre)
{
  __shared__ unsigned short As[128][40];
  __shared__ unsigned short Bs[128][40];
  const int t    = threadIdx.x;
  const int n0   = blockIdx.x * 128;
  const int m0   = blockIdx.y * 128;
  const int wave = t >> 6, lane = t & 63;
  const int wr   = (wave >> 1) * 64;
  const int wc   = (wave & 1) * 64;
  const int lcol = lane & 15, quad = lane >> 4;
  floatx4 acc[4][4] = {};

  for (int kk = 0; kk < H_; kk += 32) {
    __syncthreads();
#pragma unroll
    for (int i = 0; i < 4; i++) {
      int idx = t + i * 256;
      int row = idx >> 3, k4 = (idx & 7) << 2;
      float4 v = *reinterpret_cast<const float4*>(x + (size_t)(m0 + row) * H_ + kk + k4);
      unsigned lo = f2bf(v.x) | (f2bf(v.y) << 16);
      unsigned hi = f2bf(v.z) | (f2bf(v.w) << 16);
      *reinterpret_cast<uint2*>(&As[row][k4]) = make_uint2(lo, hi);
    }
#pragma unroll
    for (int i = 0; i < 4; i++) {
      int idx = t + i * 256;
      int kr = idx >> 5, c4 = (idx & 31) << 2;
      float4 v = *reinterpret_cast<const float4*>(W1 + (size_t)(kk + kr) * HH + n0 + c4);
      Bs[c4 + 0][kr] = (unsigned short)f2bf(v.x);
      Bs[c4 + 1][kr] = (unsigned short)f2bf(v.y);
      Bs[c4 + 2][kr] = (unsigned short)f2bf(v.z);
      Bs[c4 + 3][kr] = (unsigned short)f2bf(v.w);
    }
    __syncthreads();
    bf16x8 af[4], bfr[4];
#pragma unroll
    for (int mt = 0; mt < 4; mt++)
      af[mt] = *reinterpret_cast<const bf16x8*>(&As[wr + mt * 16 + lcol][quad * 8]);
#pragma unroll
    for (int nt = 0; nt < 4; nt++)
      bfr[nt] = *reinterpret_cast<const bf16x8*>(&Bs[wc + nt * 16 + lcol][quad * 8]);
#pragma unroll
    for (int mt = 0; mt < 4; mt++)
#pragma unroll
      for (int nt = 0; nt < 4; nt++)
        acc[mt][nt] = __builtin_amdgcn_mfma_f32_16x16x32_bf16(af[mt], bfr[nt], acc[mt][nt], 0, 0, 0);
  }
  float rowsum[4][4];
#pragma unroll
  for (int mt = 0; mt < 4; mt++)
#pragma unroll
    for (int r = 0; r < 4; r++) rowsum[mt][r] = 0.f;
#pragma unroll
  for (int nt = 0; nt < 4; nt++) {
    int n = n0 + wc + nt * 16 + lcol;
    float b1v = b1[n], w2v = W2[n];
#pragma unroll
    for (int mt = 0; mt < 4; mt++)
#pragma unroll
      for (int r = 0; r < 4; r++) {
        float h = fmaxf(acc[mt][nt][r] + b1v, 0.f);
        rowsum[mt][r] = fmaf(h, w2v, rowsum[mt][r]);
      }
  }
#pragma unroll
  for (int mt = 0; mt < 4; mt++)
#pragma unroll
    for (int r = 0; r < 4; r++) {
      float s = rowsum[mt][r];
      s += __shfl_xor(s, 1); s += __shfl_xor(s, 2);
      s += __shfl_xor(s, 4); s += __shfl_xor(s, 8);
      if (lcol == 0)
        atomicAdd(&s_pre[m0 + wr + mt * 16 + quad * 4 + r], s);
    }
}

// ---------------------------------------------------------------------------
// K2: sigmoid/threshold, masked exp(importance), global Z and event count.
// ---------------------------------------------------------------------------
__global__ __launch_bounds__(256) void score_kernel(
    const float* __restrict__ s_pre, const float* __restrict__ imp,
    const float* __restrict__ b2, float* __restrict__ wbuf,
    float* __restrict__ Z, float* __restrict__ cnt)
{
  int i = blockIdx.x * 256 + threadIdx.x;
  float s = s_pre[i] + b2[0];
  float sig = 1.f / (1.f + __expf(-s));
  bool ev = sig > 0.7f;
  float w = ev ? __expf(imp[i]) : 0.f;
  wbuf[i] = w;
  float cw = ev ? 1.f : 0.f;
#pragma unroll
  for (int off = 32; off; off >>= 1) {
    w  += __shfl_down(w, off);
    cw += __shfl_down(cw, off);
  }
  if ((threadIdx.x & 63) == 0) {
    atomicAdd(Z, w);
    atomicAdd(cnt, cw);
  }
}

// ---------------------------------------------------------------------------
// K3: c[j] = sum_i wbuf[i] * x[i][j]   (512 blocks x 32 rows: full-CU coverage)
// ---------------------------------------------------------------------------
__global__ __launch_bounds__(256) void consolidate_kernel(
    const float* __restrict__ x, const float* __restrict__ wbuf,
    float* __restrict__ c)
{
  int t = threadIdx.x;
  int r0 = blockIdx.x * 32;
  float a[8] = {0.f, 0.f, 0.f, 0.f, 0.f, 0.f, 0.f, 0.f};
  for (int r = 0; r < 32; r++) {
    float w = wbuf[r0 + r];
    if (w != 0.f) {
      const float4* xr = reinterpret_cast<const float4*>(x + (size_t)(r0 + r) * H_);
      float4 v0 = xr[t], v1 = xr[t + 256];
      a[0] = fmaf(w, v0.x, a[0]); a[1] = fmaf(w, v0.y, a[1]);
      a[2] = fmaf(w, v0.z, a[2]); a[3] = fmaf(w, v0.w, a[3]);
      a[4] = fmaf(w, v1.x, a[4]); a[5] = fmaf(w, v1.y, a[5]);
      a[6] = fmaf(w, v1.z, a[6]); a[7] = fmaf(w, v1.w, a[7]);
    }
  }
  int j0 = t * 4;
  atomicAdd(&c[j0 + 0], a[0]); atomicAdd(&c[j0 + 1], a[1]);
  atomicAdd(&c[j0 + 2], a[2]); atomicAdd(&c[j0 + 3], a[3]);
  atomicAdd(&c[1024 + j0 + 0], a[4]); atomicAdd(&c[1024 + j0 + 1], a[5]);
  atomicAdd(&c[1024 + j0 + 2], a[6]); atomicAdd(&c[1024 + j0 + 3], a[7]);
}

// ---------------------------------------------------------------------------
// K4: hr[n] += (c/Z) . W_r1[:,n]
// ---------------------------------------------------------------------------
__global__ __launch_bounds__(256) void r1_kernel(
    const float* __restrict__ c, const float* __restrict__ Z,
    const float* __restrict__ cnt, const float* __restrict__ Wr1,
    float* __restrict__ hr)
{
  __shared__ float cs[128];
  int n  = blockIdx.x * 256 + threadIdx.x;
  int k0 = blockIdx.y * 128;
  float inv = (cnt[0] > 0.5f) ? (1.f / Z[0]) : 0.f;
  if (threadIdx.x < 128) cs[threadIdx.x] = c[k0 + threadIdx.x] * inv;
  __syncthreads();
  float s = 0.f;
#pragma unroll 8
  for (int k = 0; k < 128; k++)
    s = fmaf(cs[k], Wr1[(size_t)(k0 + k) * HH + n], s);
  atomicAdd(&hr[n], s);
}

// ---------------------------------------------------------------------------
// K5: rt[n] += relu(hr + b_r1) . W_r2[:,n]
// ---------------------------------------------------------------------------
__global__ __launch_bounds__(256) void r2_kernel(
    const float* __restrict__ hr, const float* __restrict__ br1,
    const float* __restrict__ Wr2, float* __restrict__ rt)
{
  __shared__ float hs[128];
  int n  = blockIdx.x * 256 + threadIdx.x;
  int k0 = blockIdx.y * 128;
  if (threadIdx.x < 128)
    hs[threadIdx.x] = fmaxf(hr[k0 + threadIdx.x] + br1[k0 + threadIdx.x], 0.f);
  __syncthreads();
  float s = 0.f;
#pragma unroll 8
  for (int k = 0; k < 128; k++)
    s = fmaf(hs[k], Wr2[(size_t)(k0 + k) * H_ + n], s);
  atomicAdd(&rt[n], s);
}

// ---------------------------------------------------------------------------
// K6: add[j] = has_events ? sigmoid(rt[j] + b_r2[j]) : 0
// ---------------------------------------------------------------------------
__global__ __launch_bounds__(256) void finalize_kernel(
    const float* __restrict__ rt, const float* __restrict__ br2,
    const float* __restrict__ cnt, float* __restrict__ addv)
{
  int j = blockIdx.x * 256 + threadIdx.x;
  float v = 0.f;
  if (cnt[0] > 0.5f) v = 1.f / (1.f + expf(-(rt[j] + br2[j])));
  addv[j] = v;
}

// ---------------------------------------------------------------------------
// K7: out = x + add (broadcast over rows)
// ---------------------------------------------------------------------------
__global__ __launch_bounds__(256) void out_kernel(
    const float* __restrict__ x, const float* __restrict__ addv,
    float* __restrict__ out)
{
  size_t i = (size_t)blockIdx.x * 256 + threadIdx.x;
  int j4 = (int)(i & 511);
  float4 a = reinterpret_cast<const float4*>(addv)[j4];
  float4 v = reinterpret_cast<const float4*>(x)[i];
  v.x += a.x; v.y += a.y; v.z += a.z; v.w += a.w;
  reinterpret_cast<float4*>(out)[i] = v;
}

// ---------------------------------------------------------------------------
extern "C" void kernel_launch(void* const* d_in, const int* in_sizes, int n_in,
                              void* d_out, int out_size, void* d_ws, size_t ws_size,
                              hipStream_t stream)
{
  (void)in_sizes; (void)n_in; (void)out_size;
  const float* x   = (const float*)d_in[0];
  const float* imp = (const float*)d_in[1];
  const float* We1 = (const float*)d_in[2];
  const float* be1 = (const float*)d_in[3];
  const float* We2 = (const float*)d_in[4];
  const float* be2 = (const float*)d_in[5];
  const float* Wr1 = (const float*)d_in[6];
  const float* br1 = (const float*)d_in[7];
  const float* Wr2 = (const float*)d_in[8];
  const float* br2 = (const float*)d_in[9];
  float* out = (float*)d_out;

  float* ws    = (float*)d_ws;
  float* s_pre = ws;            // 16384
  float* c     = ws + 16384;    // 2048
  float* hr    = ws + 18432;    // 1024
  float* rt    = ws + 19456;    // 2048
  float* Z     = ws + 21504;    // 1
  float* cnt   = ws + 21505;    // 1
  float* wbuf  = ws + 21760;    // 16384 (fully written, no init)
  float* addv  = ws + 38144;    // 2048  (fully written, no init)

  const size_t scal_bytes = 49152 * sizeof(float);             // 196608 B
  const size_t xb_bytes   = (size_t)NROWS * H_ * 2;            // 67.1 MB
  const size_t w1t_bytes  = (size_t)HH * H_ * 2;               // 4.2 MB
  unsigned short* xb  = (unsigned short*)((char*)d_ws + scal_bytes);
  unsigned short* W1t = (unsigned short*)((char*)d_ws + scal_bytes + xb_bytes);
  const bool fast = ws_size >= scal_bytes + xb_bytes + w1t_bytes;

  hipMemsetAsync(d_ws, 0, 21506 * sizeof(float), stream);

  if (fast) {
    convert_x_kernel<<<16384, 256, 0, stream>>>(x, xb);
    transpose_w1_kernel<<<dim3(32, 16), 256, 0, stream>>>(We1, W1t);
    gemm_v2_kernel<<<dim3(128, 8), 256, 0, stream>>>(xb, W1t, be1, We2, s_pre);
  } else {
    gemm_score_kernel<<<dim3(8, 128), 256, 0, stream>>>(x, We1, be1, We2, s_pre);
  }
  score_kernel<<<64, 256, 0, stream>>>(s_pre, imp, be2, wbuf, Z, cnt);
  consolidate_kernel<<<512, 256, 0, stream>>>(x, wbuf, c);
  r1_kernel<<<dim3(4, 16), 256, 0, stream>>>(c, Z, cnt, Wr1, hr);
  r2_kernel<<<dim3(8, 8), 256, 0, stream>>>(hr, br1, Wr2, rt);
  finalize_kernel<<<8, 256, 0, stream>>>(rt, br2, cnt, addv);
  out_kernel<<<32768, 256, 0, stream>>>(x, addv, out);
}

// Round 2
// 443.378 us; speedup vs baseline: 1.0571x; 1.0287x over previous
//
#include <hip/hip_runtime.h>
#include <hip/hip_bf16.h>

#define H_    2048
#define NROWS 16384
#define HH    1024

typedef __bf16 bf16x8 __attribute__((ext_vector_type(8)));
typedef float  floatx4 __attribute__((ext_vector_type(4)));

__device__ __forceinline__ unsigned f2bf(float f) {
  unsigned u = __builtin_bit_cast(unsigned, f);
  u += 0x7fff + ((u >> 16) & 1);          // round-nearest-even to bf16
  return u >> 16;
}

__device__ __forceinline__ void gload_lds16(const void* g, void* l) {
  // 16B per lane, lands at wave-uniform LDS base + lane*16
  __builtin_amdgcn_global_load_lds(
      (const __attribute__((address_space(1))) unsigned*)g,
      (__attribute__((address_space(3))) unsigned*)l, 16, 0, 0);
}

// ---------------------------------------------------------------------------
// Kc: x fp32 -> xb bf16 (row-major, same layout). Grid-stride, 2048 blocks.
// ---------------------------------------------------------------------------
__global__ __launch_bounds__(256) void convert_x_kernel(
    const float* __restrict__ x, unsigned short* __restrict__ xb)
{
  size_t base = ((size_t)blockIdx.x * 256 + threadIdx.x) * 8;
#pragma unroll
  for (int it = 0; it < 8; ++it) {
    size_t i = base + (size_t)it * (524288u * 8);
    float4 v0 = *reinterpret_cast<const float4*>(x + i);
    float4 v1 = *reinterpret_cast<const float4*>(x + i + 4);
    uint4 o;
    o.x = f2bf(v0.x) | (f2bf(v0.y) << 16);
    o.y = f2bf(v0.z) | (f2bf(v0.w) << 16);
    o.z = f2bf(v1.x) | (f2bf(v1.y) << 16);
    o.w = f2bf(v1.z) | (f2bf(v1.w) << 16);
    *reinterpret_cast<uint4*>(xb + i) = o;
  }
}

// ---------------------------------------------------------------------------
// Kt: W1 [k=2048][n=1024] fp32 -> W1t [n][k] bf16 via LDS tile transpose.
// ---------------------------------------------------------------------------
__global__ __launch_bounds__(256) void transpose_w1_kernel(
    const float* __restrict__ W1, unsigned short* __restrict__ W1t)
{
  __shared__ unsigned short tile[64][66];   // [k][n], pad 66 -> conflict-free col reads
  int k0 = blockIdx.x * 64;                 // 32
  int n0 = blockIdx.y * 64;                 // 16
  int t = threadIdx.x;
#pragma unroll
  for (int i = 0; i < 4; i++) {
    int idx = t + i * 256;
    int r = idx >> 4, c4 = (idx & 15) << 2;
    float4 v = *reinterpret_cast<const float4*>(W1 + (size_t)(k0 + r) * HH + n0 + c4);
    tile[r][c4 + 0] = (unsigned short)f2bf(v.x);
    tile[r][c4 + 1] = (unsigned short)f2bf(v.y);
    tile[r][c4 + 2] = (unsigned short)f2bf(v.z);
    tile[r][c4 + 3] = (unsigned short)f2bf(v.w);
  }
  __syncthreads();
#pragma unroll
  for (int i = 0; i < 2; i++) {
    int idx = t + i * 256;
    int n = idx >> 3, k8 = (idx & 7) << 3;
    uint4 o;
    o.x = (unsigned)tile[k8 + 0][n] | ((unsigned)tile[k8 + 1][n] << 16);
    o.y = (unsigned)tile[k8 + 2][n] | ((unsigned)tile[k8 + 3][n] << 16);
    o.z = (unsigned)tile[k8 + 4][n] | ((unsigned)tile[k8 + 5][n] << 16);
    o.w = (unsigned)tile[k8 + 6][n] | ((unsigned)tile[k8 + 7][n] << 16);
    *reinterpret_cast<uint4*>(W1t + (size_t)(n0 + n) * H_ + k0 + k8) = o;
  }
}

// ---------------------------------------------------------------------------
// K1 (fast): bf16 MFMA GEMM, 128x128 tile, BK=64, global_load_lds with
// both-sides XOR swizzle (conflict-free ds_read_b128), m-major grid for
// XCD L2 locality, fused relu(+b1)*W2 row-reduction epilogue -> s_pre.
// ---------------------------------------------------------------------------
__global__ __launch_bounds__(256) void gemm_v2_kernel(
    const unsigned short* __restrict__ xb, const unsigned short* __restrict__ W1t,
    const float* __restrict__ b1, const float* __restrict__ W2,
    float* __restrict__ s_pre)
{
  __shared__ unsigned short As[128 * 64];   // [m][k], chunk q stored at q^(row&7)
  __shared__ unsigned short Bs[128 * 64];   // [n][k], same swizzle

  const int t    = threadIdx.x;
  const int m0   = blockIdx.x * 128;  // m-major: linear id = m + 128*n, id%8 = m%8
  const int n0   = blockIdx.y * 128;  //  -> all 8 n-blocks of an m-panel share an XCD
  const int wave = t >> 6, lane = t & 63;
  const int wr   = (wave >> 1) * 64;
  const int wc   = (wave & 1) * 64;
  const int lcol = lane & 15, quad = lane >> 4;

  floatx4 acc[4][4] = {};

  const int srow = t >> 3;
  const int sq   = (t & 7) ^ (srow & 7);
  const unsigned short* ag = xb  + (size_t)(m0 + srow) * H_ + sq * 8;
  const unsigned short* bg = W1t + (size_t)(n0 + srow) * H_ + sq * 8;
  unsigned short* al = As + 512 * wave;     // + lane*16B by HW
  unsigned short* bl = Bs + 512 * wave;

  for (int kk = 0; kk < H_; kk += 64) {
    __syncthreads();
#pragma unroll
    for (int j = 0; j < 4; j++) {
      gload_lds16(ag + kk + (size_t)(32 * j) * H_, al + 2048 * j);
      gload_lds16(bg + kk + (size_t)(32 * j) * H_, bl + 2048 * j);
    }
    __syncthreads();

#pragma unroll
    for (int h = 0; h < 2; h++) {           // two k=32 halves of the BK=64 tile
      bf16x8 af[4], bfr[4];
#pragma unroll
      for (int mt = 0; mt < 4; mt++) {
        int r = wr + mt * 16 + lcol;
        af[mt] = *reinterpret_cast<const bf16x8*>(
            As + r * 64 + ((((h << 2) | quad) ^ (r & 7)) << 3));
      }
#pragma unroll
      for (int nt = 0; nt < 4; nt++) {
        int r = wc + nt * 16 + lcol;
        bfr[nt] = *reinterpret_cast<const bf16x8*>(
            Bs + r * 64 + ((((h << 2) | quad) ^ (r & 7)) << 3));
      }
#pragma unroll
      for (int mt = 0; mt < 4; mt++)
#pragma unroll
        for (int nt = 0; nt < 4; nt++)
          acc[mt][nt] = __builtin_amdgcn_mfma_f32_16x16x32_bf16(af[mt], bfr[nt], acc[mt][nt], 0, 0, 0);
    }
  }

  // epilogue: relu(acc + b1[n]) * W2[n] summed over this block's 128 n-cols
  float rowsum[4][4];
#pragma unroll
  for (int mt = 0; mt < 4; mt++)
#pragma unroll
    for (int r = 0; r < 4; r++) rowsum[mt][r] = 0.f;

#pragma unroll
  for (int nt = 0; nt < 4; nt++) {
    int n = n0 + wc + nt * 16 + lcol;      // C/D col = lane&15
    float b1v = b1[n], w2v = W2[n];
#pragma unroll
    for (int mt = 0; mt < 4; mt++)
#pragma unroll
      for (int r = 0; r < 4; r++) {
        float h = fmaxf(acc[mt][nt][r] + b1v, 0.f);
        rowsum[mt][r] = fmaf(h, w2v, rowsum[mt][r]);
      }
  }
#pragma unroll
  for (int mt = 0; mt < 4; mt++)
#pragma unroll
    for (int r = 0; r < 4; r++) {
      float s = rowsum[mt][r];
      s += __shfl_xor(s, 1); s += __shfl_xor(s, 2);
      s += __shfl_xor(s, 4); s += __shfl_xor(s, 8);
      if (lcol == 0)
        atomicAdd(&s_pre[m0 + wr + mt * 16 + quad * 4 + r], s);  // C/D row = quad*4+r
    }
}

// ---------------------------------------------------------------------------
// K1 (fallback, small ws): round-1 fused GEMM with in-loop conversion.
// ---------------------------------------------------------------------------
__global__ __launch_bounds__(256) void gemm_score_kernel(
    const float* __restrict__ x, const float* __restrict__ W1,
    const float* __restrict__ b1, const float* __restrict__ W2,
    float* __restrict__ s_pre)
{
  __shared__ unsigned short As[128][40];
  __shared__ unsigned short Bs[128][40];
  const int t    = threadIdx.x;
  const int n0   = blockIdx.x * 128;
  const int m0   = blockIdx.y * 128;
  const int wave = t >> 6, lane = t & 63;
  const int wr   = (wave >> 1) * 64;
  const int wc   = (wave & 1) * 64;
  const int lcol = lane & 15, quad = lane >> 4;
  floatx4 acc[4][4] = {};

  for (int kk = 0; kk < H_; kk += 32) {
    __syncthreads();
#pragma unroll
    for (int i = 0; i < 4; i++) {
      int idx = t + i * 256;
      int row = idx >> 3, k4 = (idx & 7) << 2;
      float4 v = *reinterpret_cast<const float4*>(x + (size_t)(m0 + row) * H_ + kk + k4);
      unsigned lo = f2bf(v.x) | (f2bf(v.y) << 16);
      unsigned hi = f2bf(v.z) | (f2bf(v.w) << 16);
      *reinterpret_cast<uint2*>(&As[row][k4]) = make_uint2(lo, hi);
    }
#pragma unroll
    for (int i = 0; i < 4; i++) {
      int idx = t + i * 256;
      int kr = idx >> 5, c4 = (idx & 31) << 2;
      float4 v = *reinterpret_cast<const float4*>(W1 + (size_t)(kk + kr) * HH + n0 + c4);
      Bs[c4 + 0][kr] = (unsigned short)f2bf(v.x);
      Bs[c4 + 1][kr] = (unsigned short)f2bf(v.y);
      Bs[c4 + 2][kr] = (unsigned short)f2bf(v.z);
      Bs[c4 + 3][kr] = (unsigned short)f2bf(v.w);
    }
    __syncthreads();
    bf16x8 af[4], bfr[4];
#pragma unroll
    for (int mt = 0; mt < 4; mt++)
      af[mt] = *reinterpret_cast<const bf16x8*>(&As[wr + mt * 16 + lcol][quad * 8]);
#pragma unroll
    for (int nt = 0; nt < 4; nt++)
      bfr[nt] = *reinterpret_cast<const bf16x8*>(&Bs[wc + nt * 16 + lcol][quad * 8]);
#pragma unroll
    for (int mt = 0; mt < 4; mt++)
#pragma unroll
      for (int nt = 0; nt < 4; nt++)
        acc[mt][nt] = __builtin_amdgcn_mfma_f32_16x16x32_bf16(af[mt], bfr[nt], acc[mt][nt], 0, 0, 0);
  }
  float rowsum[4][4];
#pragma unroll
  for (int mt = 0; mt < 4; mt++)
#pragma unroll
    for (int r = 0; r < 4; r++) rowsum[mt][r] = 0.f;
#pragma unroll
  for (int nt = 0; nt < 4; nt++) {
    int n = n0 + wc + nt * 16 + lcol;
    float b1v = b1[n], w2v = W2[n];
#pragma unroll
    for (int mt = 0; mt < 4; mt++)
#pragma unroll
      for (int r = 0; r < 4; r++) {
        float h = fmaxf(acc[mt][nt][r] + b1v, 0.f);
        rowsum[mt][r] = fmaf(h, w2v, rowsum[mt][r]);
      }
  }
#pragma unroll
  for (int mt = 0; mt < 4; mt++)
#pragma unroll
    for (int r = 0; r < 4; r++) {
      float s = rowsum[mt][r];
      s += __shfl_xor(s, 1); s += __shfl_xor(s, 2);
      s += __shfl_xor(s, 4); s += __shfl_xor(s, 8);
      if (lcol == 0)
        atomicAdd(&s_pre[m0 + wr + mt * 16 + quad * 4 + r], s);
    }
}

// ---------------------------------------------------------------------------
// K2+K3 fused: per-block (64 rows) compute event weights (wave 0) + block's
// partial of c into a PRIVATE slice (plain stores — no atomic contention).
// Z/cnt: 2 atomics per block.
// ---------------------------------------------------------------------------
__global__ __launch_bounds__(256) void consolidate_partial_kernel(
    const float* __restrict__ x, const float* __restrict__ s_pre,
    const float* __restrict__ imp, const float* __restrict__ b2,
    float* __restrict__ part, float* __restrict__ Z, float* __restrict__ cnt)
{
  __shared__ float wl[64];
  int t  = threadIdx.x;
  int r0 = blockIdx.x * 64;
  if (t < 64) {                                // wave 0 exactly
    float s   = s_pre[r0 + t] + b2[0];
    float sig = 1.f / (1.f + __expf(-s));
    bool  ev  = sig > 0.7f;
    float w   = ev ? __expf(imp[r0 + t]) : 0.f;
    wl[t] = w;
    float cw = ev ? 1.f : 0.f;
#pragma unroll
    for (int off = 32; off; off >>= 1) {
      w  += __shfl_down(w, off);
      cw += __shfl_down(cw, off);
    }
    if (t == 0) { atomicAdd(Z, w); atomicAdd(cnt, cw); }
  }
  __syncthreads();

  float a[8] = {0.f, 0.f, 0.f, 0.f, 0.f, 0.f, 0.f, 0.f};
  for (int r = 0; r < 64; ++r) {
    float w = wl[r];
    if (w != 0.f) {
      const float4* xr = reinterpret_cast<const float4*>(x + (size_t)(r0 + r) * H_);
      float4 v0 = xr[t], v1 = xr[t + 256];
      a[0] = fmaf(w, v0.x, a[0]); a[1] = fmaf(w, v0.y, a[1]);
      a[2] = fmaf(w, v0.z, a[2]); a[3] = fmaf(w, v0.w, a[3]);
      a[4] = fmaf(w, v1.x, a[4]); a[5] = fmaf(w, v1.y, a[5]);
      a[6] = fmaf(w, v1.z, a[6]); a[7] = fmaf(w, v1.w, a[7]);
    }
  }
  size_t base = (size_t)blockIdx.x * 2048;
  int j0 = t * 4;
  part[base + j0 + 0] = a[0]; part[base + j0 + 1] = a[1];
  part[base + j0 + 2] = a[2]; part[base + j0 + 3] = a[3];
  part[base + 1024 + j0 + 0] = a[4]; part[base + 1024 + j0 + 1] = a[5];
  part[base + 1024 + j0 + 2] = a[6]; part[base + 1024 + j0 + 3] = a[7];
}

// ---------------------------------------------------------------------------
// K3b: c[j] = sum over 256 block-partials (2 MB, plain reads, no atomics)
// ---------------------------------------------------------------------------
__global__ __launch_bounds__(256) void reduce_c_kernel(
    const float* __restrict__ part, float* __restrict__ c)
{
  int j = blockIdx.x * 256 + threadIdx.x;   // 8 blocks x 256 = 2048
  float s = 0.f;
#pragma unroll 8
  for (int b = 0; b < 256; ++b)
    s += part[(size_t)b * 2048 + j];
  c[j] = s;
}

// ---------------------------------------------------------------------------
// K2 (fallback path only): sigmoid/threshold, masked exp(importance).
// ---------------------------------------------------------------------------
__global__ __launch_bounds__(256) void score_kernel(
    const float* __restrict__ s_pre, const float* __restrict__ imp,
    const float* __restrict__ b2, float* __restrict__ wbuf,
    float* __restrict__ Z, float* __restrict__ cnt)
{
  int i = blockIdx.x * 256 + threadIdx.x;
  float s = s_pre[i] + b2[0];
  float sig = 1.f / (1.f + __expf(-s));
  bool ev = sig > 0.7f;
  float w = ev ? __expf(imp[i]) : 0.f;
  wbuf[i] = w;
  float cw = ev ? 1.f : 0.f;
#pragma unroll
  for (int off = 32; off; off >>= 1) {
    w  += __shfl_down(w, off);
    cw += __shfl_down(cw, off);
  }
  if ((threadIdx.x & 63) == 0) {
    atomicAdd(Z, w);
    atomicAdd(cnt, cw);
  }
}

// ---------------------------------------------------------------------------
// K3 (fallback path only): atomic consolidate.
// ---------------------------------------------------------------------------
__global__ __launch_bounds__(256) void consolidate_kernel(
    const float* __restrict__ x, const float* __restrict__ wbuf,
    float* __restrict__ c)
{
  int t = threadIdx.x;
  int r0 = blockIdx.x * 128;
  float a[8] = {0.f, 0.f, 0.f, 0.f, 0.f, 0.f, 0.f, 0.f};
  for (int r = 0; r < 128; r++) {
    float w = wbuf[r0 + r];
    if (w != 0.f) {
      const float4* xr = reinterpret_cast<const float4*>(x + (size_t)(r0 + r) * H_);
      float4 v0 = xr[t], v1 = xr[t + 256];
      a[0] = fmaf(w, v0.x, a[0]); a[1] = fmaf(w, v0.y, a[1]);
      a[2] = fmaf(w, v0.z, a[2]); a[3] = fmaf(w, v0.w, a[3]);
      a[4] = fmaf(w, v1.x, a[4]); a[5] = fmaf(w, v1.y, a[5]);
      a[6] = fmaf(w, v1.z, a[6]); a[7] = fmaf(w, v1.w, a[7]);
    }
  }
  int j0 = t * 4;
  atomicAdd(&c[j0 + 0], a[0]); atomicAdd(&c[j0 + 1], a[1]);
  atomicAdd(&c[j0 + 2], a[2]); atomicAdd(&c[j0 + 3], a[3]);
  atomicAdd(&c[1024 + j0 + 0], a[4]); atomicAdd(&c[1024 + j0 + 1], a[5]);
  atomicAdd(&c[1024 + j0 + 2], a[6]); atomicAdd(&c[1024 + j0 + 3], a[7]);
}

// ---------------------------------------------------------------------------
// K4: hr[n] += (c/Z) . W_r1[:,n]
// ---------------------------------------------------------------------------
__global__ __launch_bounds__(256) void r1_kernel(
    const float* __restrict__ c, const float* __restrict__ Z,
    const float* __restrict__ cnt, const float* __restrict__ Wr1,
    float* __restrict__ hr)
{
  __shared__ float cs[128];
  int n  = blockIdx.x * 256 + threadIdx.x;
  int k0 = blockIdx.y * 128;
  float inv = (cnt[0] > 0.5f) ? (1.f / Z[0]) : 0.f;
  if (threadIdx.x < 128) cs[threadIdx.x] = c[k0 + threadIdx.x] * inv;
  __syncthreads();
  float s = 0.f;
#pragma unroll 8
  for (int k = 0; k < 128; k++)
    s = fmaf(cs[k], Wr1[(size_t)(k0 + k) * HH + n], s);
  atomicAdd(&hr[n], s);
}

// ---------------------------------------------------------------------------
// K5: rt[n] += relu(hr + b_r1) . W_r2[:,n]
// ---------------------------------------------------------------------------
__global__ __launch_bounds__(256) void r2_kernel(
    const float* __restrict__ hr, const float* __restrict__ br1,
    const float* __restrict__ Wr2, float* __restrict__ rt)
{
  __shared__ float hs[128];
  int n  = blockIdx.x * 256 + threadIdx.x;
  int k0 = blockIdx.y * 128;
  if (threadIdx.x < 128)
    hs[threadIdx.x] = fmaxf(hr[k0 + threadIdx.x] + br1[k0 + threadIdx.x], 0.f);
  __syncthreads();
  float s = 0.f;
#pragma unroll 8
  for (int k = 0; k < 128; k++)
    s = fmaf(hs[k], Wr2[(size_t)(k0 + k) * H_ + n], s);
  atomicAdd(&rt[n], s);
}

// ---------------------------------------------------------------------------
// K6: add[j] = has_events ? sigmoid(rt[j] + b_r2[j]) : 0
// ---------------------------------------------------------------------------
__global__ __launch_bounds__(256) void finalize_kernel(
    const float* __restrict__ rt, const float* __restrict__ br2,
    const float* __restrict__ cnt, float* __restrict__ addv)
{
  int j = blockIdx.x * 256 + threadIdx.x;
  float v = 0.f;
  if (cnt[0] > 0.5f) v = 1.f / (1.f + expf(-(rt[j] + br2[j])));
  addv[j] = v;
}

// ---------------------------------------------------------------------------
// K7: out = x + add (broadcast over rows). Grid-stride, addv loop-invariant.
// ---------------------------------------------------------------------------
__global__ __launch_bounds__(256) void out_kernel(
    const float* __restrict__ x, const float* __restrict__ addv,
    float* __restrict__ out)
{
  size_t base = (size_t)blockIdx.x * 256 + threadIdx.x;   // 0..524287 (float4 idx)
  float4 a = reinterpret_cast<const float4*>(addv)[(int)(base & 511)];
#pragma unroll
  for (int it = 0; it < 16; ++it) {
    size_t i = base + (size_t)it * 524288u;   // stride % 512 == 0 -> same addv elem
    float4 v = reinterpret_cast<const float4*>(x)[i];
    v.x += a.x; v.y += a.y; v.z += a.z; v.w += a.w;
    reinterpret_cast<float4*>(out)[i] = v;
  }
}

// ---------------------------------------------------------------------------
extern "C" void kernel_launch(void* const* d_in, const int* in_sizes, int n_in,
                              void* d_out, int out_size, void* d_ws, size_t ws_size,
                              hipStream_t stream)
{
  (void)in_sizes; (void)n_in; (void)out_size;
  const float* x   = (const float*)d_in[0];
  const float* imp = (const float*)d_in[1];
  const float* We1 = (const float*)d_in[2];
  const float* be1 = (const float*)d_in[3];
  const float* We2 = (const float*)d_in[4];
  const float* be2 = (const float*)d_in[5];
  const float* Wr1 = (const float*)d_in[6];
  const float* br1 = (const float*)d_in[7];
  const float* Wr2 = (const float*)d_in[8];
  const float* br2 = (const float*)d_in[9];
  float* out = (float*)d_out;

  float* ws    = (float*)d_ws;
  float* s_pre = ws;            // 16384
  float* c     = ws + 16384;    // 2048
  float* hr    = ws + 18432;    // 1024
  float* rt    = ws + 19456;    // 2048
  float* Z     = ws + 21504;    // 1
  float* cnt   = ws + 21505;    // 1
  float* wbuf  = ws + 21760;    // 16384 (fallback path only)
  float* addv  = ws + 38144;    // 2048  (fully written, no init)

  const size_t scal_bytes = 49152 * sizeof(float);             // 196608 B
  const size_t xb_bytes   = (size_t)NROWS * H_ * 2;            // 67.1 MB
  const size_t w1t_bytes  = (size_t)HH * H_ * 2;               // 4.2 MB
  unsigned short* xb  = (unsigned short*)((char*)d_ws + scal_bytes);
  unsigned short* W1t = (unsigned short*)((char*)d_ws + scal_bytes + xb_bytes);
  // xb is dead after the gemm -> reuse its storage for the 256x2048 partials
  float* part = (float*)xb;
  const bool fast = ws_size >= scal_bytes + xb_bytes + w1t_bytes;

  hipMemsetAsync(d_ws, 0, 21506 * sizeof(float), stream);

  if (fast) {
    convert_x_kernel<<<2048, 256, 0, stream>>>(x, xb);
    transpose_w1_kernel<<<dim3(32, 16), 256, 0, stream>>>(We1, W1t);
    gemm_v2_kernel<<<dim3(128, 8), 256, 0, stream>>>(xb, W1t, be1, We2, s_pre);
    consolidate_partial_kernel<<<256, 256, 0, stream>>>(x, s_pre, imp, be2, part, Z, cnt);
    reduce_c_kernel<<<8, 256, 0, stream>>>(part, c);
  } else {
    gemm_score_kernel<<<dim3(8, 128), 256, 0, stream>>>(x, We1, be1, We2, s_pre);
    score_kernel<<<64, 256, 0, stream>>>(s_pre, imp, be2, wbuf, Z, cnt);
    consolidate_kernel<<<128, 256, 0, stream>>>(x, wbuf, c);
  }
  r1_kernel<<<dim3(4, 16), 256, 0, stream>>>(c, Z, cnt, Wr1, hr);
  r2_kernel<<<dim3(8, 8), 256, 0, stream>>>(hr, br1, Wr2, rt);
  finalize_kernel<<<8, 256, 0, stream>>>(rt, br2, cnt, addv);
  out_kernel<<<2048, 256, 0, stream>>>(x, addv, out);
}

// Round 4
// 436.995 us; speedup vs baseline: 1.0725x; 1.0146x over previous
//
#include <hip/hip_runtime.h>
#include <hip/hip_bf16.h>

#define H_    2048
#define NROWS 16384
#define HH    1024

typedef __bf16 bf16x8 __attribute__((ext_vector_type(8)));
typedef float  floatx4 __attribute__((ext_vector_type(4)));
typedef unsigned short ushortx8 __attribute__((ext_vector_type(8)));

__device__ __forceinline__ unsigned f2bf(float f) {
  unsigned u = __builtin_bit_cast(unsigned, f);
  u += 0x7fff + ((u >> 16) & 1);          // round-nearest-even to bf16
  return u >> 16;
}

__device__ __forceinline__ float bf2f(unsigned short u) {
  return __builtin_bit_cast(float, (unsigned)u << 16);
}

__device__ __forceinline__ void gload_lds16(const void* g, void* l) {
  // 16B per lane, lands at wave-uniform LDS base + lane*16
  __builtin_amdgcn_global_load_lds(
      (const __attribute__((address_space(1))) unsigned*)g,
      (__attribute__((address_space(3))) unsigned*)l, 16, 0, 0);
}

// ---------------------------------------------------------------------------
// Kc: x fp32 -> xb bf16 (row-major, same layout). Grid-stride, 2048 blocks.
// ---------------------------------------------------------------------------
__global__ __launch_bounds__(256) void convert_x_kernel(
    const float* __restrict__ x, unsigned short* __restrict__ xb)
{
  size_t base = ((size_t)blockIdx.x * 256 + threadIdx.x) * 8;
#pragma unroll
  for (int it = 0; it < 8; ++it) {
    size_t i = base + (size_t)it * (524288u * 8);
    float4 v0 = *reinterpret_cast<const float4*>(x + i);
    float4 v1 = *reinterpret_cast<const float4*>(x + i + 4);
    uint4 o;
    o.x = f2bf(v0.x) | (f2bf(v0.y) << 16);
    o.y = f2bf(v0.z) | (f2bf(v0.w) << 16);
    o.z = f2bf(v1.x) | (f2bf(v1.y) << 16);
    o.w = f2bf(v1.z) | (f2bf(v1.w) << 16);
    *reinterpret_cast<uint4*>(xb + i) = o;
  }
}

// ---------------------------------------------------------------------------
// Kt: W1 [k=2048][n=1024] fp32 -> W1t [n][k] bf16 via LDS tile transpose.
// ---------------------------------------------------------------------------
__global__ __launch_bounds__(256) void transpose_w1_kernel(
    const float* __restrict__ W1, unsigned short* __restrict__ W1t)
{
  __shared__ unsigned short tile[64][66];
  int k0 = blockIdx.x * 64;
  int n0 = blockIdx.y * 64;
  int t = threadIdx.x;
#pragma unroll
  for (int i = 0; i < 4; i++) {
    int idx = t + i * 256;
    int r = idx >> 4, c4 = (idx & 15) << 2;
    float4 v = *reinterpret_cast<const float4*>(W1 + (size_t)(k0 + r) * HH + n0 + c4);
    tile[r][c4 + 0] = (unsigned short)f2bf(v.x);
    tile[r][c4 + 1] = (unsigned short)f2bf(v.y);
    tile[r][c4 + 2] = (unsigned short)f2bf(v.z);
    tile[r][c4 + 3] = (unsigned short)f2bf(v.w);
  }
  __syncthreads();
#pragma unroll
  for (int i = 0; i < 2; i++) {
    int idx = t + i * 256;
    int n = idx >> 3, k8 = (idx & 7) << 3;
    uint4 o;
    o.x = (unsigned)tile[k8 + 0][n] | ((unsigned)tile[k8 + 1][n] << 16);
    o.y = (unsigned)tile[k8 + 2][n] | ((unsigned)tile[k8 + 3][n] << 16);
    o.z = (unsigned)tile[k8 + 4][n] | ((unsigned)tile[k8 + 5][n] << 16);
    o.w = (unsigned)tile[k8 + 6][n] | ((unsigned)tile[k8 + 7][n] << 16);
    *reinterpret_cast<uint4*>(W1t + (size_t)(n0 + n) * H_ + k0 + k8) = o;
  }
}

// ---------------------------------------------------------------------------
// K1 (fast): 256x256-tile 8-phase bf16 MFMA GEMM (T2 swizzle + T3/T4 counted
// vmcnt + T5 setprio), 512 threads (8 waves, 2M x 4N), BK=64, 128 KiB LDS,
// fused relu(+b1)*W2 row-reduction epilogue -> s_pre.
// Schedule (vmcnt accounting verified; steady state 6 outstanding loads):
//   stage slots/iter: P0:A[1]h1(Tb)  P2:B[0]h0  P3:B[0]h1+A[0]h0  P4:A[0]h1
//                     P6:B[1]h0      P7:B[1]h1+A[1]h0        (tiles Ta+2/Tb+2)
//   vmcnt(6) checkpoints at P3->P4 and P7->P0 boundaries.
// Main loop is split 15+1 manually (no unswitch / unroll blow-up).
// ---------------------------------------------------------------------------
__global__ __launch_bounds__(512, 2) void gemm_v3_kernel(
    const unsigned short* __restrict__ xb, const unsigned short* __restrict__ W1t,
    const float* __restrict__ b1, const float* __restrict__ W2,
    float* __restrict__ s_pre)
{
  __shared__ unsigned short LA[2][2][8192];  // [tile-parity][half][128*64]
  __shared__ unsigned short LB[2][2][8192];

  const int t    = threadIdx.x;
  const int m0   = blockIdx.x * 256;   // m-major grid: XCD = bx%8 -> L2 locality
  const int n0   = blockIdx.y * 256;
  const int w    = t >> 6, lane = t & 63;
  const int wm   = w >> 2;             // A half (row group of 128)
  const int wn   = w & 3;              // col group of 64
  const int bh   = wn >> 1;            // B half
  const int bc0  = (wn & 1) * 64;      // col base within B half
  const int lcol = lane & 15, quad = lane >> 4;
  const int sx   = lane & 7;           // read-side swizzle XOR

  // staging: half-tile = 128 rows x 64 k; thread stages chunks {w*64+lane, +512}
  // row rloc (+64 for 2nd), slot q=lane&7, global source chunk = q^(row&7)
  const int rloc = w * 8 + (lane >> 3);
  const int qoff = ((lane & 7) ^ (rloc & 7)) * 8;
  const unsigned short* aS = xb  + (size_t)(m0 + rloc) * H_ + qoff;
  const unsigned short* bS = W1t + (size_t)(n0 + rloc) * H_ + qoff;
  const int wj0 = w * 512, wj1 = 4096 + w * 512;   // wave-uniform LDS dests

  floatx4 acc[8][4] = {};
  bf16x8 af[4][2];        // current A m-group: 4 frags x 2 k-halves
  bf16x8 bq[2][2][2];     // B groups: [ng][ni][kh]

#define STG_A(P, h, T) do { \
    gload_lds16(aS + (size_t)((h) * 128) * H_ + (T) * 64,        &LA[P][h][wj0]); \
    gload_lds16(aS + (size_t)((h) * 128 + 64) * H_ + (T) * 64,   &LA[P][h][wj1]); } while (0)
#define STG_B(P, h, T) do { \
    gload_lds16(bS + (size_t)((h) * 128) * H_ + (T) * 64,        &LB[P][h][wj0]); \
    gload_lds16(bS + (size_t)((h) * 128 + 64) * H_ + (T) * 64,   &LB[P][h][wj1]); } while (0)

#define RD_A4(P, base) do { _Pragma("unroll") \
    for (int mi = 0; mi < 4; ++mi) { \
      const int rr = ((base) + mi) * 16 + lcol; \
      af[mi][0] = *reinterpret_cast<const bf16x8*>(&LA[P][wm][rr * 64 + ((quad) ^ sx) * 8]); \
      af[mi][1] = *reinterpret_cast<const bf16x8*>(&LA[P][wm][rr * 64 + ((4 + quad) ^ sx) * 8]); } } while (0)
#define RD_B2(P, g) do { _Pragma("unroll") \
    for (int ni = 0; ni < 2; ++ni) { \
      const int cc = bc0 + ((g) * 2 + ni) * 16 + lcol; \
      bq[g][ni][0] = *reinterpret_cast<const bf16x8*>(&LB[P][bh][cc * 64 + ((quad) ^ sx) * 8]); \
      bq[g][ni][1] = *reinterpret_cast<const bf16x8*>(&LB[P][bh][cc * 64 + ((4 + quad) ^ sx) * 8]); } } while (0)

#define MFMA_Q(mg, ng) do { _Pragma("unroll") \
    for (int mi = 0; mi < 4; ++mi) { _Pragma("unroll") \
      for (int ni = 0; ni < 2; ++ni) { \
        acc[(mg)*4+mi][(ng)*2+ni] = __builtin_amdgcn_mfma_f32_16x16x32_bf16(af[mi][0], bq[ng][ni][0], acc[(mg)*4+mi][(ng)*2+ni], 0, 0, 0); \
        acc[(mg)*4+mi][(ng)*2+ni] = __builtin_amdgcn_mfma_f32_16x16x32_bf16(af[mi][1], bq[ng][ni][1], acc[(mg)*4+mi][(ng)*2+ni], 0, 0, 0); } } } while (0)

#define PH_PRE() do { asm volatile("" ::: "memory"); __builtin_amdgcn_s_barrier(); \
    asm volatile("s_waitcnt lgkmcnt(0)" ::: "memory"); \
    __builtin_amdgcn_sched_barrier(0); __builtin_amdgcn_s_setprio(1); } while (0)
#define PH_POST() do { __builtin_amdgcn_s_setprio(0); \
    asm volatile("" ::: "memory"); __builtin_amdgcn_s_barrier(); } while (0)

#define CKPT(ST) do { \
    __builtin_amdgcn_s_setprio(0); \
    if (ST) asm volatile("s_waitcnt vmcnt(6)" ::: "memory"); \
    else    asm volatile("s_waitcnt vmcnt(0)" ::: "memory"); \
    asm volatile("" ::: "memory"); __builtin_amdgcn_s_barrier(); } while (0)

#define BODY(Ta, Tb, ST) do { \
    /* P0: read A[0]g0 + B[0]g0 ; stage A[1]h1 <- Tb */ \
    RD_A4(0, 0); RD_B2(0, 0); \
    STG_A(1, 1, Tb); \
    PH_PRE(); MFMA_Q(0, 0); PH_POST(); \
    /* P1: read B[0]g1 */ \
    RD_B2(0, 1); \
    PH_PRE(); MFMA_Q(0, 1); PH_POST(); \
    /* P2: read A[0]g1 ; stage B[0]h0 <- Ta+2 */ \
    RD_A4(0, 4); \
    if (ST) STG_B(0, 0, (Ta) + 2); \
    PH_PRE(); MFMA_Q(1, 1); PH_POST(); \
    /* P3: stage B[0]h1 + A[0]h0 <- Ta+2 ; checkpoint */ \
    if (ST) { STG_B(0, 1, (Ta) + 2); STG_A(0, 0, (Ta) + 2); } \
    PH_PRE(); MFMA_Q(1, 0); CKPT(ST); \
    /* P4: read A[1]g0 + B[1]g0 ; stage A[0]h1 <- Ta+2 */ \
    RD_A4(1, 0); RD_B2(1, 0); \
    if (ST) STG_A(0, 1, (Ta) + 2); \
    PH_PRE(); MFMA_Q(0, 0); PH_POST(); \
    /* P5: read B[1]g1 */ \
    RD_B2(1, 1); \
    PH_PRE(); MFMA_Q(0, 1); PH_POST(); \
    /* P6: read A[1]g1 ; stage B[1]h0 <- Tb+2 */ \
    RD_A4(1, 4); \
    if (ST) STG_B(1, 0, (Tb) + 2); \
    PH_PRE(); MFMA_Q(1, 1); PH_POST(); \
    /* P7: stage B[1]h1 + A[1]h0 <- Tb+2 ; checkpoint */ \
    if (ST) { STG_B(1, 1, (Tb) + 2); STG_A(1, 0, (Tb) + 2); } \
    PH_PRE(); MFMA_Q(1, 0); CKPT(ST); } while (0)

  // prologue: T0 full + T1 {Bh0,Bh1,Ah0}; vmcnt(6) => own T0 loads landed;
  // barrier combines per-wave guarantees -> T0 fully in LDS.
  STG_A(0, 0, 0); STG_A(0, 1, 0); STG_B(0, 0, 0); STG_B(0, 1, 0);
  STG_B(1, 0, 1); STG_B(1, 1, 1); STG_A(1, 0, 1);
  asm volatile("s_waitcnt vmcnt(6)" ::: "memory");
  __builtin_amdgcn_s_barrier();

#pragma unroll 1
  for (int i = 0; i < 15; ++i) {
    BODY(2 * i, 2 * i + 1, 1);
  }
  BODY(30, 31, 0);   // drain iteration: no prefetch, vmcnt(0) checkpoints

#undef STG_A
#undef STG_B
#undef RD_A4
#undef RD_B2
#undef MFMA_Q
#undef PH_PRE
#undef PH_POST
#undef CKPT
#undef BODY

  // epilogue: relu(acc + b1[n]) * W2[n] summed over this block's 256 n-cols
  float rs[8][4] = {};
#pragma unroll
  for (int nf = 0; nf < 4; ++nf) {
    int n = n0 + wn * 64 + nf * 16 + lcol;        // C/D col = lane&15
    float b1v = b1[n], w2v = W2[n];
#pragma unroll
    for (int mf = 0; mf < 8; ++mf)
#pragma unroll
      for (int r = 0; r < 4; ++r)
        rs[mf][r] = fmaf(fmaxf(acc[mf][nf][r] + b1v, 0.f), w2v, rs[mf][r]);
  }
#pragma unroll
  for (int mf = 0; mf < 8; ++mf)
#pragma unroll
    for (int r = 0; r < 4; ++r) {
      float s = rs[mf][r];
      s += __shfl_xor(s, 1); s += __shfl_xor(s, 2);
      s += __shfl_xor(s, 4); s += __shfl_xor(s, 8);
      if (lcol == 0)
        atomicAdd(&s_pre[m0 + wm * 128 + mf * 16 + quad * 4 + r], s);
    }
}

// ---------------------------------------------------------------------------
// K1 (fallback, small ws): round-1 fused GEMM with in-loop conversion.
// ---------------------------------------------------------------------------
__global__ __launch_bounds__(256) void gemm_score_kernel(
    const float* __restrict__ x, const float* __restrict__ W1,
    const float* __restrict__ b1, const float* __restrict__ W2,
    float* __restrict__ s_pre)
{
  __shared__ unsigned short As[128][40];
  __shared__ unsigned short Bs[128][40];
  const int t    = threadIdx.x;
  const int n0   = blockIdx.x * 128;
  const int m0   = blockIdx.y * 128;
  const int wave = t >> 6, lane = t & 63;
  const int wr   = (wave >> 1) * 64;
  const int wc   = (wave & 1) * 64;
  const int lcol = lane & 15, quad = lane >> 4;
  floatx4 acc[4][4] = {};

  for (int kk = 0; kk < H_; kk += 32) {
    __syncthreads();
#pragma unroll
    for (int i = 0; i < 4; i++) {
      int idx = t + i * 256;
      int row = idx >> 3, k4 = (idx & 7) << 2;
      float4 v = *reinterpret_cast<const float4*>(x + (size_t)(m0 + row) * H_ + kk + k4);
      unsigned lo = f2bf(v.x) | (f2bf(v.y) << 16);
      unsigned hi = f2bf(v.z) | (f2bf(v.w) << 16);
      *reinterpret_cast<uint2*>(&As[row][k4]) = make_uint2(lo, hi);
    }
#pragma unroll
    for (int i = 0; i < 4; i++) {
      int idx = t + i * 256;
      int kr = idx >> 5, c4 = (idx & 31) << 2;
      float4 v = *reinterpret_cast<const float4*>(W1 + (size_t)(kk + kr) * HH + n0 + c4);
      Bs[c4 + 0][kr] = (unsigned short)f2bf(v.x);
      Bs[c4 + 1][kr] = (unsigned short)f2bf(v.y);
      Bs[c4 + 2][kr] = (unsigned short)f2bf(v.z);
      Bs[c4 + 3][kr] = (unsigned short)f2bf(v.w);
    }
    __syncthreads();
    bf16x8 af[4], bfr[4];
#pragma unroll
    for (int mt = 0; mt < 4; mt++)
      af[mt] = *reinterpret_cast<const bf16x8*>(&As[wr + mt * 16 + lcol][quad * 8]);
#pragma unroll
    for (int nt = 0; nt < 4; nt++)
      bfr[nt] = *reinterpret_cast<const bf16x8*>(&Bs[wc + nt * 16 + lcol][quad * 8]);
#pragma unroll
    for (int mt = 0; mt < 4; mt++)
#pragma unroll
      for (int nt = 0; nt < 4; nt++)
        acc[mt][nt] = __builtin_amdgcn_mfma_f32_16x16x32_bf16(af[mt], bfr[nt], acc[mt][nt], 0, 0, 0);
  }
  float rowsum[4][4];
#pragma unroll
  for (int mt = 0; mt < 4; mt++)
#pragma unroll
    for (int r = 0; r < 4; r++) rowsum[mt][r] = 0.f;
#pragma unroll
  for (int nt = 0; nt < 4; nt++) {
    int n = n0 + wc + nt * 16 + lcol;
    float b1v = b1[n], w2v = W2[n];
#pragma unroll
    for (int mt = 0; mt < 4; mt++)
#pragma unroll
      for (int r = 0; r < 4; r++) {
        float h = fmaxf(acc[mt][nt][r] + b1v, 0.f);
        rowsum[mt][r] = fmaf(h, w2v, rowsum[mt][r]);
      }
  }
#pragma unroll
  for (int mt = 0; mt < 4; mt++)
#pragma unroll
    for (int r = 0; r < 4; r++) {
      float s = rowsum[mt][r];
      s += __shfl_xor(s, 1); s += __shfl_xor(s, 2);
      s += __shfl_xor(s, 4); s += __shfl_xor(s, 8);
      if (lcol == 0)
        atomicAdd(&s_pre[m0 + wr + mt * 16 + quad * 4 + r], s);
    }
}

// ---------------------------------------------------------------------------
// K2+K3 fused: per-block (64 rows) event weights (wave 0) + block's partial
// of c from xb (bf16) into a PRIVATE slice (plain stores, no contention).
// ---------------------------------------------------------------------------
__global__ __launch_bounds__(256) void consolidate_partial_kernel(
    const unsigned short* __restrict__ xb, const float* __restrict__ s_pre,
    const float* __restrict__ imp, const float* __restrict__ b2,
    float* __restrict__ part, float* __restrict__ Z, float* __restrict__ cnt)
{
  __shared__ float wl[64];
  int t  = threadIdx.x;
  int r0 = blockIdx.x * 64;
  if (t < 64) {                                // wave 0 exactly
    float s   = s_pre[r0 + t] + b2[0];
    float sig = 1.f / (1.f + __expf(-s));
    bool  ev  = sig > 0.7f;
    float w   = ev ? __expf(imp[r0 + t]) : 0.f;
    wl[t] = w;
    float cw = ev ? 1.f : 0.f;
#pragma unroll
    for (int off = 32; off; off >>= 1) {
      w  += __shfl_down(w, off);
      cw += __shfl_down(cw, off);
    }
    if (t == 0) { atomicAdd(Z, w); atomicAdd(cnt, cw); }
  }
  __syncthreads();

  float a[8] = {0.f, 0.f, 0.f, 0.f, 0.f, 0.f, 0.f, 0.f};
  for (int r = 0; r < 64; ++r) {
    float w = wl[r];
    if (w != 0.f) {
      ushortx8 v = *reinterpret_cast<const ushortx8*>(
          xb + (size_t)(r0 + r) * H_ + t * 8);
#pragma unroll
      for (int e = 0; e < 8; ++e) a[e] = fmaf(w, bf2f(v[e]), a[e]);
    }
  }
  size_t base = (size_t)blockIdx.x * 2048 + t * 8;
#pragma unroll
  for (int e = 0; e < 8; ++e) part[base + e] = a[e];
}

// ---------------------------------------------------------------------------
// K3b: c[j] = sum over 256 block-partials (2 MB, plain reads, no atomics)
// ---------------------------------------------------------------------------
__global__ __launch_bounds__(256) void reduce_c_kernel(
    const float* __restrict__ part, float* __restrict__ c)
{
  int j = blockIdx.x * 256 + threadIdx.x;   // 8 blocks x 256 = 2048
  float s = 0.f;
#pragma unroll 8
  for (int b = 0; b < 256; ++b)
    s += part[(size_t)b * 2048 + j];
  c[j] = s;
}

// ---------------------------------------------------------------------------
// K2 (fallback path only)
// ---------------------------------------------------------------------------
__global__ __launch_bounds__(256) void score_kernel(
    const float* __restrict__ s_pre, const float* __restrict__ imp,
    const float* __restrict__ b2, float* __restrict__ wbuf,
    float* __restrict__ Z, float* __restrict__ cnt)
{
  int i = blockIdx.x * 256 + threadIdx.x;
  float s = s_pre[i] + b2[0];
  float sig = 1.f / (1.f + __expf(-s));
  bool ev = sig > 0.7f;
  float w = ev ? __expf(imp[i]) : 0.f;
  wbuf[i] = w;
  float cw = ev ? 1.f : 0.f;
#pragma unroll
  for (int off = 32; off; off >>= 1) {
    w  += __shfl_down(w, off);
    cw += __shfl_down(cw, off);
  }
  if ((threadIdx.x & 63) == 0) {
    atomicAdd(Z, w);
    atomicAdd(cnt, cw);
  }
}

// ---------------------------------------------------------------------------
// K3 (fallback path only): atomic consolidate from fp32 x.
// ---------------------------------------------------------------------------
__global__ __launch_bounds__(256) void consolidate_kernel(
    const float* __restrict__ x, const float* __restrict__ wbuf,
    float* __restrict__ c)
{
  int t = threadIdx.x;
  int r0 = blockIdx.x * 128;
  float a[8] = {0.f, 0.f, 0.f, 0.f, 0.f, 0.f, 0.f, 0.f};
  for (int r = 0; r < 128; r++) {
    float w = wbuf[r0 + r];
    if (w != 0.f) {
      const float4* xr = reinterpret_cast<const float4*>(x + (size_t)(r0 + r) * H_);
      float4 v0 = xr[t], v1 = xr[t + 256];
      a[0] = fmaf(w, v0.x, a[0]); a[1] = fmaf(w, v0.y, a[1]);
      a[2] = fmaf(w, v0.z, a[2]); a[3] = fmaf(w, v0.w, a[3]);
      a[4] = fmaf(w, v1.x, a[4]); a[5] = fmaf(w, v1.y, a[5]);
      a[6] = fmaf(w, v1.z, a[6]); a[7] = fmaf(w, v1.w, a[7]);
    }
  }
  int j0 = t * 4;
  atomicAdd(&c[j0 + 0], a[0]); atomicAdd(&c[j0 + 1], a[1]);
  atomicAdd(&c[j0 + 2], a[2]); atomicAdd(&c[j0 + 3], a[3]);
  atomicAdd(&c[1024 + j0 + 0], a[4]); atomicAdd(&c[1024 + j0 + 1], a[5]);
  atomicAdd(&c[1024 + j0 + 2], a[6]); atomicAdd(&c[1024 + j0 + 3], a[7]);
}

// ---------------------------------------------------------------------------
// K4: hr[n] += (c/Z) . W_r1[:,n]
// ---------------------------------------------------------------------------
__global__ __launch_bounds__(256) void r1_kernel(
    const float* __restrict__ c, const float* __restrict__ Z,
    const float* __restrict__ cnt, const float* __restrict__ Wr1,
    float* __restrict__ hr)
{
  __shared__ float cs[128];
  int n  = blockIdx.x * 256 + threadIdx.x;
  int k0 = blockIdx.y * 128;
  float inv = (cnt[0] > 0.5f) ? (1.f / Z[0]) : 0.f;
  if (threadIdx.x < 128) cs[threadIdx.x] = c[k0 + threadIdx.x] * inv;
  __syncthreads();
  float s = 0.f;
#pragma unroll 8
  for (int k = 0; k < 128; k++)
    s = fmaf(cs[k], Wr1[(size_t)(k0 + k) * HH + n], s);
  atomicAdd(&hr[n], s);
}

// ---------------------------------------------------------------------------
// K5: rt[n] += relu(hr + b_r1) . W_r2[:,n]
// ---------------------------------------------------------------------------
__global__ __launch_bounds__(256) void r2_kernel(
    const float* __restrict__ hr, const float* __restrict__ br1,
    const float* __restrict__ Wr2, float* __restrict__ rt)
{
  __shared__ float hs[128];
  int n  = blockIdx.x * 256 + threadIdx.x;
  int k0 = blockIdx.y * 128;
  if (threadIdx.x < 128)
    hs[threadIdx.x] = fmaxf(hr[k0 + threadIdx.x] + br1[k0 + threadIdx.x], 0.f);
  __syncthreads();
  float s = 0.f;
#pragma unroll 8
  for (int k = 0; k < 128; k++)
    s = fmaf(hs[k], Wr2[(size_t)(k0 + k) * H_ + n], s);
  atomicAdd(&rt[n], s);
}

// ---------------------------------------------------------------------------
// K6: add[j] = has_events ? sigmoid(rt[j] + b_r2[j]) : 0
// ---------------------------------------------------------------------------
__global__ __launch_bounds__(256) void finalize_kernel(
    const float* __restrict__ rt, const float* __restrict__ br2,
    const float* __restrict__ cnt, float* __restrict__ addv)
{
  int j = blockIdx.x * 256 + threadIdx.x;
  float v = 0.f;
  if (cnt[0] > 0.5f) v = 1.f / (1.f + expf(-(rt[j] + br2[j])));
  addv[j] = v;
}

// ---------------------------------------------------------------------------
// K7: out = x + add (broadcast over rows). Grid-stride, addv loop-invariant.
// ---------------------------------------------------------------------------
__global__ __launch_bounds__(256) void out_kernel(
    const float* __restrict__ x, const float* __restrict__ addv,
    float* __restrict__ out)
{
  size_t base = (size_t)blockIdx.x * 256 + threadIdx.x;   // float4 index
  float4 a = reinterpret_cast<const float4*>(addv)[(int)(base & 511)];
#pragma unroll
  for (int it = 0; it < 16; ++it) {
    size_t i = base + (size_t)it * 524288u;   // stride % 512 == 0 -> same addv
    float4 v = reinterpret_cast<const float4*>(x)[i];
    v.x += a.x; v.y += a.y; v.z += a.z; v.w += a.w;
    reinterpret_cast<float4*>(out)[i] = v;
  }
}

// ---------------------------------------------------------------------------
extern "C" void kernel_launch(void* const* d_in, const int* in_sizes, int n_in,
                              void* d_out, int out_size, void* d_ws, size_t ws_size,
                              hipStream_t stream)
{
  (void)in_sizes; (void)n_in; (void)out_size;
  const float* x   = (const float*)d_in[0];
  const float* imp = (const float*)d_in[1];
  const float* We1 = (const float*)d_in[2];
  const float* be1 = (const float*)d_in[3];
  const float* We2 = (const float*)d_in[4];
  const float* be2 = (const float*)d_in[5];
  const float* Wr1 = (const float*)d_in[6];
  const float* br1 = (const float*)d_in[7];
  const float* Wr2 = (const float*)d_in[8];
  const float* br2 = (const float*)d_in[9];
  float* out = (float*)d_out;

  float* ws    = (float*)d_ws;
  float* s_pre = ws;            // 16384
  float* c     = ws + 16384;    // 2048
  float* hr    = ws + 18432;    // 1024
  float* rt    = ws + 19456;    // 2048
  float* Z     = ws + 21504;    // 1
  float* cnt   = ws + 21505;    // 1
  float* wbuf  = ws + 21760;    // 16384 (fallback path only)
  float* addv  = ws + 38144;    // 2048  (fully written, no init)

  const size_t scal_bytes = 49152 * sizeof(float);             // 196608 B
  const size_t xb_bytes   = (size_t)NROWS * H_ * 2;            // 67.1 MB
  const size_t w1t_bytes  = (size_t)HH * H_ * 2;               // 4.2 MB
  unsigned short* xb  = (unsigned short*)((char*)d_ws + scal_bytes);
  unsigned short* W1t = (unsigned short*)((char*)d_ws + scal_bytes + xb_bytes);
  // W1t is dead after the gemm -> reuse its storage for the 256x2048 partials
  float* part = (float*)W1t;
  const bool fast = ws_size >= scal_bytes + xb_bytes + w1t_bytes;

  hipMemsetAsync(d_ws, 0, 21506 * sizeof(float), stream);

  if (fast) {
    convert_x_kernel<<<2048, 256, 0, stream>>>(x, xb);
    transpose_w1_kernel<<<dim3(32, 16), 256, 0, stream>>>(We1, W1t);
    gemm_v3_kernel<<<dim3(64, 4), 512, 0, stream>>>(xb, W1t, be1, We2, s_pre);
    consolidate_partial_kernel<<<256, 256, 0, stream>>>(xb, s_pre, imp, be2, part, Z, cnt);
    reduce_c_kernel<<<8, 256, 0, stream>>>(part, c);
  } else {
    gemm_score_kernel<<<dim3(8, 128), 256, 0, stream>>>(x, We1, be1, We2, s_pre);
    score_kernel<<<64, 256, 0, stream>>>(s_pre, imp, be2, wbuf, Z, cnt);
    consolidate_kernel<<<128, 256, 0, stream>>>(x, wbuf, c);
  }
  r1_kernel<<<dim3(4, 16), 256, 0, stream>>>(c, Z, cnt, Wr1, hr);
  r2_kernel<<<dim3(8, 8), 256, 0, stream>>>(hr, br1, Wr2, rt);
  finalize_kernel<<<8, 256, 0, stream>>>(rt, br2, cnt, addv);
  out_kernel<<<2048, 256, 0, stream>>>(x, addv, out);
}

// Round 5
// 434.231 us; speedup vs baseline: 1.0793x; 1.0064x over previous
//
#include <hip/hip_runtime.h>
#include <hip/hip_bf16.h>

#define H_    2048
#define NROWS 16384
#define HH    1024

typedef __bf16 bf16x8 __attribute__((ext_vector_type(8)));
typedef float  floatx4 __attribute__((ext_vector_type(4)));
typedef unsigned short ushortx8 __attribute__((ext_vector_type(8)));

__device__ __forceinline__ unsigned f2bf(float f) {
  unsigned u = __builtin_bit_cast(unsigned, f);
  u += 0x7fff + ((u >> 16) & 1);          // round-nearest-even to bf16
  return u >> 16;
}

__device__ __forceinline__ float bf2f(unsigned short u) {
  return __builtin_bit_cast(float, (unsigned)u << 16);
}

__device__ __forceinline__ void gload_lds16(const void* g, void* l) {
  // 16B per lane, lands at wave-uniform LDS base + lane*16
  __builtin_amdgcn_global_load_lds(
      (const __attribute__((address_space(1))) unsigned*)g,
      (__attribute__((address_space(3))) unsigned*)l, 16, 0, 0);
}

// ---------------------------------------------------------------------------
// Kc: x fp32 -> xb bf16 (row-major, same layout). Grid-stride, 2048 blocks.
// ---------------------------------------------------------------------------
__global__ __launch_bounds__(256) void convert_x_kernel(
    const float* __restrict__ x, unsigned short* __restrict__ xb)
{
  size_t base = ((size_t)blockIdx.x * 256 + threadIdx.x) * 8;
#pragma unroll
  for (int it = 0; it < 8; ++it) {
    size_t i = base + (size_t)it * (524288u * 8);
    float4 v0 = *reinterpret_cast<const float4*>(x + i);
    float4 v1 = *reinterpret_cast<const float4*>(x + i + 4);
    uint4 o;
    o.x = f2bf(v0.x) | (f2bf(v0.y) << 16);
    o.y = f2bf(v0.z) | (f2bf(v0.w) << 16);
    o.z = f2bf(v1.x) | (f2bf(v1.y) << 16);
    o.w = f2bf(v1.z) | (f2bf(v1.w) << 16);
    *reinterpret_cast<uint4*>(xb + i) = o;
  }
}

// ---------------------------------------------------------------------------
// Kt: W1 [k=2048][n=1024] fp32 -> W1t [n][k] bf16 via LDS tile transpose.
// ---------------------------------------------------------------------------
__global__ __launch_bounds__(256) void transpose_w1_kernel(
    const float* __restrict__ W1, unsigned short* __restrict__ W1t)
{
  __shared__ unsigned short tile[64][66];
  int k0 = blockIdx.x * 64;
  int n0 = blockIdx.y * 64;
  int t = threadIdx.x;
#pragma unroll
  for (int i = 0; i < 4; i++) {
    int idx = t + i * 256;
    int r = idx >> 4, c4 = (idx & 15) << 2;
    float4 v = *reinterpret_cast<const float4*>(W1 + (size_t)(k0 + r) * HH + n0 + c4);
    tile[r][c4 + 0] = (unsigned short)f2bf(v.x);
    tile[r][c4 + 1] = (unsigned short)f2bf(v.y);
    tile[r][c4 + 2] = (unsigned short)f2bf(v.z);
    tile[r][c4 + 3] = (unsigned short)f2bf(v.w);
  }
  __syncthreads();
#pragma unroll
  for (int i = 0; i < 2; i++) {
    int idx = t + i * 256;
    int n = idx >> 3, k8 = (idx & 7) << 3;
    uint4 o;
    o.x = (unsigned)tile[k8 + 0][n] | ((unsigned)tile[k8 + 1][n] << 16);
    o.y = (unsigned)tile[k8 + 2][n] | ((unsigned)tile[k8 + 3][n] << 16);
    o.z = (unsigned)tile[k8 + 4][n] | ((unsigned)tile[k8 + 5][n] << 16);
    o.w = (unsigned)tile[k8 + 6][n] | ((unsigned)tile[k8 + 7][n] << 16);
    *reinterpret_cast<uint4*>(W1t + (size_t)(n0 + n) * H_ + k0 + k8) = o;
  }
}

// ---------------------------------------------------------------------------
// K1 (fast): 256x256-tile 8-phase bf16 MFMA GEMM, 512 threads (8 waves,
// 2M x 4N), BK=64, 128 KiB LDS, swizzled conflict-free ds_read_b128,
// counted-vmcnt prefetch (T4), setprio (T5), MINIMAL barriers:
//   - 2 vmcnt(6) checkpoints per iter (RAW: retire exactly the tile about
//     to be read -- accounting verified, tight)
//   - 4 WAR fences (lgkmcnt(0)+s_barrier) after P1,P2,P5,P6, i.e. between a
//     region's last ds_read-drain and the phase that re-stages it
//   - NO barrier at P0->P1 / P4->P5: read-read only, lets the 12-read burst
//     pipeline under adjacent MFMA clusters via wave skew
//   - no sched_barrier / blanket lgkm drains (compiler emits precise waits)
// Fused relu(+b1)*W2 row-reduction epilogue -> s_pre.
// ---------------------------------------------------------------------------
__global__ __launch_bounds__(512, 2) void gemm_v3_kernel(
    const unsigned short* __restrict__ xb, const unsigned short* __restrict__ W1t,
    const float* __restrict__ b1, const float* __restrict__ W2,
    float* __restrict__ s_pre)
{
  __shared__ unsigned short LA[2][2][8192];  // [tile-parity][half][128*64]
  __shared__ unsigned short LB[2][2][8192];

  const int t    = threadIdx.x;
  const int m0   = blockIdx.x * 256;   // m-major grid: XCD = bx%8 -> L2 locality
  const int n0   = blockIdx.y * 256;
  const int w    = t >> 6, lane = t & 63;
  const int wm   = w >> 2;             // A half (row group of 128)
  const int wn   = w & 3;              // col group of 64
  const int bh   = wn >> 1;            // B half
  const int bc0  = (wn & 1) * 64;      // col base within B half
  const int lcol = lane & 15, quad = lane >> 4;
  const int sx   = lane & 7;           // read-side swizzle XOR

  // staging: half-tile = 128 rows x 64 k; thread stages chunks {w*64+lane, +512}
  // row rloc (+64 for 2nd), slot q=lane&7, global source chunk = q^(row&7)
  const int rloc = w * 8 + (lane >> 3);
  const int qoff = ((lane & 7) ^ (rloc & 7)) * 8;
  const unsigned short* aS = xb  + (size_t)(m0 + rloc) * H_ + qoff;
  const unsigned short* bS = W1t + (size_t)(n0 + rloc) * H_ + qoff;
  const int wj0 = w * 512, wj1 = 4096 + w * 512;   // wave-uniform LDS dests

  floatx4 acc[8][4] = {};
  bf16x8 af[4][2];        // current A m-group: 4 frags x 2 k-halves
  bf16x8 bq[2][2][2];     // B groups: [ng][ni][kh]

#define STG_A(P, h, T) do { \
    gload_lds16(aS + (size_t)((h) * 128) * H_ + (T) * 64,        &LA[P][h][wj0]); \
    gload_lds16(aS + (size_t)((h) * 128 + 64) * H_ + (T) * 64,   &LA[P][h][wj1]); } while (0)
#define STG_B(P, h, T) do { \
    gload_lds16(bS + (size_t)((h) * 128) * H_ + (T) * 64,        &LB[P][h][wj0]); \
    gload_lds16(bS + (size_t)((h) * 128 + 64) * H_ + (T) * 64,   &LB[P][h][wj1]); } while (0)

#define RD_A4(P, base) do { _Pragma("unroll") \
    for (int mi = 0; mi < 4; ++mi) { \
      const int rr = ((base) + mi) * 16 + lcol; \
      af[mi][0] = *reinterpret_cast<const bf16x8*>(&LA[P][wm][rr * 64 + ((quad) ^ sx) * 8]); \
      af[mi][1] = *reinterpret_cast<const bf16x8*>(&LA[P][wm][rr * 64 + ((4 + quad) ^ sx) * 8]); } } while (0)
#define RD_B2(P, g) do { _Pragma("unroll") \
    for (int ni = 0; ni < 2; ++ni) { \
      const int cc = bc0 + ((g) * 2 + ni) * 16 + lcol; \
      bq[g][ni][0] = *reinterpret_cast<const bf16x8*>(&LB[P][bh][cc * 64 + ((quad) ^ sx) * 8]); \
      bq[g][ni][1] = *reinterpret_cast<const bf16x8*>(&LB[P][bh][cc * 64 + ((4 + quad) ^ sx) * 8]); } } while (0)

#define MFMA_Q(mg, ng) do { \
    __builtin_amdgcn_s_setprio(1); \
    _Pragma("unroll") \
    for (int mi = 0; mi < 4; ++mi) { _Pragma("unroll") \
      for (int ni = 0; ni < 2; ++ni) { \
        acc[(mg)*4+mi][(ng)*2+ni] = __builtin_amdgcn_mfma_f32_16x16x32_bf16(af[mi][0], bq[ng][ni][0], acc[(mg)*4+mi][(ng)*2+ni], 0, 0, 0); \
        acc[(mg)*4+mi][(ng)*2+ni] = __builtin_amdgcn_mfma_f32_16x16x32_bf16(af[mi][1], bq[ng][ni][1], acc[(mg)*4+mi][(ng)*2+ni], 0, 0, 0); } } \
    __builtin_amdgcn_s_setprio(0); } while (0)

// WAR fence: all this wave's ds_reads drained, then block-wide barrier; the
// stage issued after the barrier cannot clobber any wave's in-flight read.
#define WARB() do { asm volatile("s_waitcnt lgkmcnt(0)" ::: "memory"); \
    __builtin_amdgcn_s_barrier(); asm volatile("" ::: "memory"); } while (0)

// RAW checkpoint: counted vmcnt retires exactly the half-tiles about to be
// read (steady state: 14 outstanding -> 6); barrier publishes to all waves.
#define CKPT(ST) do { \
    if (ST) asm volatile("s_waitcnt vmcnt(6)" ::: "memory"); \
    else    asm volatile("s_waitcnt vmcnt(0)" ::: "memory"); \
    __builtin_amdgcn_s_barrier(); asm volatile("" ::: "memory"); } while (0)

#define BODY(Ta, Tb, ST) do { \
    /* P0: read Ta A-g0 + B-g0 ; stage A[1]h1 <- Tb (needed even in drain) */ \
    RD_A4(0, 0); RD_B2(0, 0); \
    STG_A(1, 1, Tb); \
    MFMA_Q(0, 0); \
    /* P1: read B-g1 (read-read vs P0 -> no barrier before) */ \
    RD_B2(0, 1); \
    MFMA_Q(0, 1); \
    WARB();  /* LB[0] fully drained before P2 re-stages it */ \
    /* P2: read A-g1 ; stage B[0]h0 <- Ta+2 */ \
    RD_A4(0, 4); \
    if (ST) STG_B(0, 0, (Ta) + 2); \
    MFMA_Q(1, 1); \
    WARB();  /* LA[0]/LB[0]h1 drained before P3 re-stages */ \
    /* P3: stage B[0]h1 + A[0]h0 <- Ta+2 ; RAW checkpoint for Tb */ \
    if (ST) { STG_B(0, 1, (Ta) + 2); STG_A(0, 0, (Ta) + 2); } \
    MFMA_Q(1, 0); \
    CKPT(ST); \
    /* P4: read Tb A-g0 + B-g0 ; stage A[0]h1 <- Ta+2 */ \
    RD_A4(1, 0); RD_B2(1, 0); \
    if (ST) STG_A(0, 1, (Ta) + 2); \
    MFMA_Q(0, 0); \
    /* P5: read B-g1 (no barrier before) */ \
    RD_B2(1, 1); \
    MFMA_Q(0, 1); \
    WARB();  /* LB[1] drained before P6 re-stages */ \
    /* P6: read A-g1 ; stage B[1]h0 <- Tb+2 */ \
    RD_A4(1, 4); \
    if (ST) STG_B(1, 0, (Tb) + 2); \
    MFMA_Q(1, 1); \
    WARB();  /* LA[1]/LB[1]h1 drained before P7 re-stages */ \
    /* P7: stage B[1]h1 + A[1]h0 <- Tb+2 ; RAW checkpoint for next Ta */ \
    if (ST) { STG_B(1, 1, (Tb) + 2); STG_A(1, 0, (Tb) + 2); } \
    MFMA_Q(1, 0); \
    CKPT(ST); } while (0)

  // prologue: T0 full + T1 {Bh0,Bh1,Ah0}; vmcnt(6) => own T0 loads landed;
  // barrier combines per-wave guarantees -> T0 fully in LDS.
  STG_A(0, 0, 0); STG_A(0, 1, 0); STG_B(0, 0, 0); STG_B(0, 1, 0);
  STG_B(1, 0, 1); STG_B(1, 1, 1); STG_A(1, 0, 1);
  asm volatile("s_waitcnt vmcnt(6)" ::: "memory");
  __builtin_amdgcn_s_barrier();
  asm volatile("" ::: "memory");

#pragma unroll 1
  for (int i = 0; i < 15; ++i) {
    BODY(2 * i, 2 * i + 1, 1);
  }
  BODY(30, 31, 0);   // drain iteration: no prefetch, vmcnt(0) checkpoints

#undef STG_A
#undef STG_B
#undef RD_A4
#undef RD_B2
#undef MFMA_Q
#undef WARB
#undef CKPT
#undef BODY

  // epilogue: relu(acc + b1[n]) * W2[n] summed over this block's 256 n-cols
  float rs[8][4] = {};
#pragma unroll
  for (int nf = 0; nf < 4; ++nf) {
    int n = n0 + wn * 64 + nf * 16 + lcol;        // C/D col = lane&15
    float b1v = b1[n], w2v = W2[n];
#pragma unroll
    for (int mf = 0; mf < 8; ++mf)
#pragma unroll
      for (int r = 0; r < 4; ++r)
        rs[mf][r] = fmaf(fmaxf(acc[mf][nf][r] + b1v, 0.f), w2v, rs[mf][r]);
  }
#pragma unroll
  for (int mf = 0; mf < 8; ++mf)
#pragma unroll
    for (int r = 0; r < 4; ++r) {
      float s = rs[mf][r];
      s += __shfl_xor(s, 1); s += __shfl_xor(s, 2);
      s += __shfl_xor(s, 4); s += __shfl_xor(s, 8);
      if (lcol == 0)
        atomicAdd(&s_pre[m0 + wm * 128 + mf * 16 + quad * 4 + r], s);
    }
}

// ---------------------------------------------------------------------------
// K1 (fallback, small ws): round-1 fused GEMM with in-loop conversion.
// ---------------------------------------------------------------------------
__global__ __launch_bounds__(256) void gemm_score_kernel(
    const float* __restrict__ x, const float* __restrict__ W1,
    const float* __restrict__ b1, const float* __restrict__ W2,
    float* __restrict__ s_pre)
{
  __shared__ unsigned short As[128][40];
  __shared__ unsigned short Bs[128][40];
  const int t    = threadIdx.x;
  const int n0   = blockIdx.x * 128;
  const int m0   = blockIdx.y * 128;
  const int wave = t >> 6, lane = t & 63;
  const int wr   = (wave >> 1) * 64;
  const int wc   = (wave & 1) * 64;
  const int lcol = lane & 15, quad = lane >> 4;
  floatx4 acc[4][4] = {};

  for (int kk = 0; kk < H_; kk += 32) {
    __syncthreads();
#pragma unroll
    for (int i = 0; i < 4; i++) {
      int idx = t + i * 256;
      int row = idx >> 3, k4 = (idx & 7) << 2;
      float4 v = *reinterpret_cast<const float4*>(x + (size_t)(m0 + row) * H_ + kk + k4);
      unsigned lo = f2bf(v.x) | (f2bf(v.y) << 16);
      unsigned hi = f2bf(v.z) | (f2bf(v.w) << 16);
      *reinterpret_cast<uint2*>(&As[row][k4]) = make_uint2(lo, hi);
    }
#pragma unroll
    for (int i = 0; i < 4; i++) {
      int idx = t + i * 256;
      int kr = idx >> 5, c4 = (idx & 31) << 2;
      float4 v = *reinterpret_cast<const float4*>(W1 + (size_t)(kk + kr) * HH + n0 + c4);
      Bs[c4 + 0][kr] = (unsigned short)f2bf(v.x);
      Bs[c4 + 1][kr] = (unsigned short)f2bf(v.y);
      Bs[c4 + 2][kr] = (unsigned short)f2bf(v.z);
      Bs[c4 + 3][kr] = (unsigned short)f2bf(v.w);
    }
    __syncthreads();
    bf16x8 af[4], bfr[4];
#pragma unroll
    for (int mt = 0; mt < 4; mt++)
      af[mt] = *reinterpret_cast<const bf16x8*>(&As[wr + mt * 16 + lcol][quad * 8]);
#pragma unroll
    for (int nt = 0; nt < 4; nt++)
      bfr[nt] = *reinterpret_cast<const bf16x8*>(&Bs[wc + nt * 16 + lcol][quad * 8]);
#pragma unroll
    for (int mt = 0; mt < 4; mt++)
#pragma unroll
      for (int nt = 0; nt < 4; nt++)
        acc[mt][nt] = __builtin_amdgcn_mfma_f32_16x16x32_bf16(af[mt], bfr[nt], acc[mt][nt], 0, 0, 0);
  }
  float rowsum[4][4];
#pragma unroll
  for (int mt = 0; mt < 4; mt++)
#pragma unroll
    for (int r = 0; r < 4; r++) rowsum[mt][r] = 0.f;
#pragma unroll
  for (int nt = 0; nt < 4; nt++) {
    int n = n0 + wc + nt * 16 + lcol;
    float b1v = b1[n], w2v = W2[n];
#pragma unroll
    for (int mt = 0; mt < 4; mt++)
#pragma unroll
      for (int r = 0; r < 4; r++) {
        float h = fmaxf(acc[mt][nt][r] + b1v, 0.f);
        rowsum[mt][r] = fmaf(h, w2v, rowsum[mt][r]);
      }
  }
#pragma unroll
  for (int mt = 0; mt < 4; mt++)
#pragma unroll
    for (int r = 0; r < 4; r++) {
      float s = rowsum[mt][r];
      s += __shfl_xor(s, 1); s += __shfl_xor(s, 2);
      s += __shfl_xor(s, 4); s += __shfl_xor(s, 8);
      if (lcol == 0)
        atomicAdd(&s_pre[m0 + wr + mt * 16 + quad * 4 + r], s);
    }
}

// ---------------------------------------------------------------------------
// K2+K3 fused: per-block (64 rows) event weights (wave 0) + block's partial
// of c from xb (bf16) into a PRIVATE slice (plain stores, no contention).
// ---------------------------------------------------------------------------
__global__ __launch_bounds__(256) void consolidate_partial_kernel(
    const unsigned short* __restrict__ xb, const float* __restrict__ s_pre,
    const float* __restrict__ imp, const float* __restrict__ b2,
    float* __restrict__ part, float* __restrict__ Z, float* __restrict__ cnt)
{
  __shared__ float wl[64];
  int t  = threadIdx.x;
  int r0 = blockIdx.x * 64;
  if (t < 64) {                                // wave 0 exactly
    float s   = s_pre[r0 + t] + b2[0];
    float sig = 1.f / (1.f + __expf(-s));
    bool  ev  = sig > 0.7f;
    float w   = ev ? __expf(imp[r0 + t]) : 0.f;
    wl[t] = w;
    float cw = ev ? 1.f : 0.f;
#pragma unroll
    for (int off = 32; off; off >>= 1) {
      w  += __shfl_down(w, off);
      cw += __shfl_down(cw, off);
    }
    if (t == 0) { atomicAdd(Z, w); atomicAdd(cnt, cw); }
  }
  __syncthreads();

  float a[8] = {0.f, 0.f, 0.f, 0.f, 0.f, 0.f, 0.f, 0.f};
  for (int r = 0; r < 64; ++r) {
    float w = wl[r];
    if (w != 0.f) {
      ushortx8 v = *reinterpret_cast<const ushortx8*>(
          xb + (size_t)(r0 + r) * H_ + t * 8);
#pragma unroll
      for (int e = 0; e < 8; ++e) a[e] = fmaf(w, bf2f(v[e]), a[e]);
    }
  }
  size_t base = (size_t)blockIdx.x * 2048 + t * 8;
#pragma unroll
  for (int e = 0; e < 8; ++e) part[base + e] = a[e];
}

// ---------------------------------------------------------------------------
// K3b: c[j] = sum over 256 block-partials (2 MB, plain reads, no atomics)
// ---------------------------------------------------------------------------
__global__ __launch_bounds__(256) void reduce_c_kernel(
    const float* __restrict__ part, float* __restrict__ c)
{
  int j = blockIdx.x * 256 + threadIdx.x;   // 8 blocks x 256 = 2048
  float s = 0.f;
#pragma unroll 8
  for (int b = 0; b < 256; ++b)
    s += part[(size_t)b * 2048 + j];
  c[j] = s;
}

// ---------------------------------------------------------------------------
// K2 (fallback path only)
// ---------------------------------------------------------------------------
__global__ __launch_bounds__(256) void score_kernel(
    const float* __restrict__ s_pre, const float* __restrict__ imp,
    const float* __restrict__ b2, float* __restrict__ wbuf,
    float* __restrict__ Z, float* __restrict__ cnt)
{
  int i = blockIdx.x * 256 + threadIdx.x;
  float s = s_pre[i] + b2[0];
  float sig = 1.f / (1.f + __expf(-s));
  bool ev = sig > 0.7f;
  float w = ev ? __expf(imp[i]) : 0.f;
  wbuf[i] = w;
  float cw = ev ? 1.f : 0.f;
#pragma unroll
  for (int off = 32; off; off >>= 1) {
    w  += __shfl_down(w, off);
    cw += __shfl_down(cw, off);
  }
  if ((threadIdx.x & 63) == 0) {
    atomicAdd(Z, w);
    atomicAdd(cnt, cw);
  }
}

// ---------------------------------------------------------------------------
// K3 (fallback path only): atomic consolidate from fp32 x.
// ---------------------------------------------------------------------------
__global__ __launch_bounds__(256) void consolidate_kernel(
    const float* __restrict__ x, const float* __restrict__ wbuf,
    float* __restrict__ c)
{
  int t = threadIdx.x;
  int r0 = blockIdx.x * 128;
  float a[8] = {0.f, 0.f, 0.f, 0.f, 0.f, 0.f, 0.f, 0.f};
  for (int r = 0; r < 128; r++) {
    float w = wbuf[r0 + r];
    if (w != 0.f) {
      const float4* xr = reinterpret_cast<const float4*>(x + (size_t)(r0 + r) * H_);
      float4 v0 = xr[t], v1 = xr[t + 256];
      a[0] = fmaf(w, v0.x, a[0]); a[1] = fmaf(w, v0.y, a[1]);
      a[2] = fmaf(w, v0.z, a[2]); a[3] = fmaf(w, v0.w, a[3]);
      a[4] = fmaf(w, v1.x, a[4]); a[5] = fmaf(w, v1.y, a[5]);
      a[6] = fmaf(w, v1.z, a[6]); a[7] = fmaf(w, v1.w, a[7]);
    }
  }
  int j0 = t * 4;
  atomicAdd(&c[j0 + 0], a[0]); atomicAdd(&c[j0 + 1], a[1]);
  atomicAdd(&c[j0 + 2], a[2]); atomicAdd(&c[j0 + 3], a[3]);
  atomicAdd(&c[1024 + j0 + 0], a[4]); atomicAdd(&c[1024 + j0 + 1], a[5]);
  atomicAdd(&c[1024 + j0 + 2], a[6]); atomicAdd(&c[1024 + j0 + 3], a[7]);
}

// ---------------------------------------------------------------------------
// K4: hr[n] += (c/Z) . W_r1[:,n]
// ---------------------------------------------------------------------------
__global__ __launch_bounds__(256) void r1_kernel(
    const float* __restrict__ c, const float* __restrict__ Z,
    const float* __restrict__ cnt, const float* __restrict__ Wr1,
    float* __restrict__ hr)
{
  __shared__ float cs[128];
  int n  = blockIdx.x * 256 + threadIdx.x;
  int k0 = blockIdx.y * 128;
  float inv = (cnt[0] > 0.5f) ? (1.f / Z[0]) : 0.f;
  if (threadIdx.x < 128) cs[threadIdx.x] = c[k0 + threadIdx.x] * inv;
  __syncthreads();
  float s = 0.f;
#pragma unroll 8
  for (int k = 0; k < 128; k++)
    s = fmaf(cs[k], Wr1[(size_t)(k0 + k) * HH + n], s);
  atomicAdd(&hr[n], s);
}

// ---------------------------------------------------------------------------
// K5: rt[n] += relu(hr + b_r1) . W_r2[:,n]
// ---------------------------------------------------------------------------
__global__ __launch_bounds__(256) void r2_kernel(
    const float* __restrict__ hr, const float* __restrict__ br1,
    const float* __restrict__ Wr2, float* __restrict__ rt)
{
  __shared__ float hs[128];
  int n  = blockIdx.x * 256 + threadIdx.x;
  int k0 = blockIdx.y * 128;
  if (threadIdx.x < 128)
    hs[threadIdx.x] = fmaxf(hr[k0 + threadIdx.x] + br1[k0 + threadIdx.x], 0.f);
  __syncthreads();
  float s = 0.f;
#pragma unroll 8
  for (int k = 0; k < 128; k++)
    s = fmaf(hs[k], Wr2[(size_t)(k0 + k) * H_ + n], s);
  atomicAdd(&rt[n], s);
}

// ---------------------------------------------------------------------------
// K6: add[j] = has_events ? sigmoid(rt[j] + b_r2[j]) : 0
// ---------------------------------------------------------------------------
__global__ __launch_bounds__(256) void finalize_kernel(
    const float* __restrict__ rt, const float* __restrict__ br2,
    const float* __restrict__ cnt, float* __restrict__ addv)
{
  int j = blockIdx.x * 256 + threadIdx.x;
  float v = 0.f;
  if (cnt[0] > 0.5f) v = 1.f / (1.f + expf(-(rt[j] + br2[j])));
  addv[j] = v;
}

// ---------------------------------------------------------------------------
// K7: out = x + add (broadcast over rows). Grid-stride, addv loop-invariant.
// ---------------------------------------------------------------------------
__global__ __launch_bounds__(256) void out_kernel(
    const float* __restrict__ x, const float* __restrict__ addv,
    float* __restrict__ out)
{
  size_t base = (size_t)blockIdx.x * 256 + threadIdx.x;   // float4 index
  float4 a = reinterpret_cast<const float4*>(addv)[(int)(base & 511)];
#pragma unroll
  for (int it = 0; it < 16; ++it) {
    size_t i = base + (size_t)it * 524288u;   // stride % 512 == 0 -> same addv
    float4 v = reinterpret_cast<const float4*>(x)[i];
    v.x += a.x; v.y += a.y; v.z += a.z; v.w += a.w;
    reinterpret_cast<float4*>(out)[i] = v;
  }
}

// ---------------------------------------------------------------------------
extern "C" void kernel_launch(void* const* d_in, const int* in_sizes, int n_in,
                              void* d_out, int out_size, void* d_ws, size_t ws_size,
                              hipStream_t stream)
{
  (void)in_sizes; (void)n_in; (void)out_size;
  const float* x   = (const float*)d_in[0];
  const float* imp = (const float*)d_in[1];
  const float* We1 = (const float*)d_in[2];
  const float* be1 = (const float*)d_in[3];
  const float* We2 = (const float*)d_in[4];
  const float* be2 = (const float*)d_in[5];
  const float* Wr1 = (const float*)d_in[6];
  const float* br1 = (const float*)d_in[7];
  const float* Wr2 = (const float*)d_in[8];
  const float* br2 = (const float*)d_in[9];
  float* out = (float*)d_out;

  float* ws    = (float*)d_ws;
  float* s_pre = ws;            // 16384
  float* c     = ws + 16384;    // 2048
  float* hr    = ws + 18432;    // 1024
  float* rt    = ws + 19456;    // 2048
  float* Z     = ws + 21504;    // 1
  float* cnt   = ws + 21505;    // 1
  float* wbuf  = ws + 21760;    // 16384 (fallback path only)
  float* addv  = ws + 38144;    // 2048  (fully written, no init)

  const size_t scal_bytes = 49152 * sizeof(float);             // 196608 B
  const size_t xb_bytes   = (size_t)NROWS * H_ * 2;            // 67.1 MB
  const size_t w1t_bytes  = (size_t)HH * H_ * 2;               // 4.2 MB
  unsigned short* xb  = (unsigned short*)((char*)d_ws + scal_bytes);
  unsigned short* W1t = (unsigned short*)((char*)d_ws + scal_bytes + xb_bytes);
  // W1t is dead after the gemm -> reuse its storage for the 256x2048 partials
  float* part = (float*)W1t;
  const bool fast = ws_size >= scal_bytes + xb_bytes + w1t_bytes;

  hipMemsetAsync(d_ws, 0, 21506 * sizeof(float), stream);

  if (fast) {
    convert_x_kernel<<<2048, 256, 0, stream>>>(x, xb);
    transpose_w1_kernel<<<dim3(32, 16), 256, 0, stream>>>(We1, W1t);
    gemm_v3_kernel<<<dim3(64, 4), 512, 0, stream>>>(xb, W1t, be1, We2, s_pre);
    consolidate_partial_kernel<<<256, 256, 0, stream>>>(xb, s_pre, imp, be2, part, Z, cnt);
    reduce_c_kernel<<<8, 256, 0, stream>>>(part, c);
  } else {
    gemm_score_kernel<<<dim3(8, 128), 256, 0, stream>>>(x, We1, be1, We2, s_pre);
    score_kernel<<<64, 256, 0, stream>>>(s_pre, imp, be2, wbuf, Z, cnt);
    consolidate_kernel<<<128, 256, 0, stream>>>(x, wbuf, c);
  }
  r1_kernel<<<dim3(4, 16), 256, 0, stream>>>(c, Z, cnt, Wr1, hr);
  r2_kernel<<<dim3(8, 8), 256, 0, stream>>>(hr, br1, Wr2, rt);
  finalize_kernel<<<8, 256, 0, stream>>>(rt, br2, cnt, addv);
  out_kernel<<<2048, 256, 0, stream>>>(x, addv, out);
}

// Round 7
// 425.922 us; speedup vs baseline: 1.1004x; 1.0195x over previous
//
#include <hip/hip_runtime.h>
#include <hip/hip_bf16.h>

#define H_    2048
#define NROWS 16384
#define HH    1024

typedef __bf16 bf16x8 __attribute__((ext_vector_type(8)));
typedef float  floatx4 __attribute__((ext_vector_type(4)));
typedef unsigned short ushortx8 __attribute__((ext_vector_type(8)));

__device__ __forceinline__ unsigned f2bf(float f) {
  unsigned u = __builtin_bit_cast(unsigned, f);
  u += 0x7fff + ((u >> 16) & 1);          // round-nearest-even to bf16
  return u >> 16;
}

__device__ __forceinline__ float bf2f(unsigned short u) {
  return __builtin_bit_cast(float, (unsigned)u << 16);
}

__device__ __forceinline__ void gload_lds16(const void* g, void* l) {
  // 16B per lane, lands at wave-uniform LDS base + lane*16
  __builtin_amdgcn_global_load_lds(
      (const __attribute__((address_space(1))) unsigned*)g,
      (__attribute__((address_space(3))) unsigned*)l, 16, 0, 0);
}

// ---------------------------------------------------------------------------
// Kc: x fp32 -> xb bf16 (row-major, same layout). Grid-stride, 2048 blocks.
// ---------------------------------------------------------------------------
__global__ __launch_bounds__(256) void convert_x_kernel(
    const float* __restrict__ x, unsigned short* __restrict__ xb)
{
  size_t base = ((size_t)blockIdx.x * 256 + threadIdx.x) * 8;
#pragma unroll
  for (int it = 0; it < 8; ++it) {
    size_t i = base + (size_t)it * (524288u * 8);
    float4 v0 = *reinterpret_cast<const float4*>(x + i);
    float4 v1 = *reinterpret_cast<const float4*>(x + i + 4);
    uint4 o;
    o.x = f2bf(v0.x) | (f2bf(v0.y) << 16);
    o.y = f2bf(v0.z) | (f2bf(v0.w) << 16);
    o.z = f2bf(v1.x) | (f2bf(v1.y) << 16);
    o.w = f2bf(v1.z) | (f2bf(v1.w) << 16);
    *reinterpret_cast<uint4*>(xb + i) = o;
  }
}

// ---------------------------------------------------------------------------
// Kt: W1 [k=2048][n=1024] fp32 -> W1t [n][k] bf16 via LDS tile transpose.
// ---------------------------------------------------------------------------
__global__ __launch_bounds__(256) void transpose_w1_kernel(
    const float* __restrict__ W1, unsigned short* __restrict__ W1t)
{
  __shared__ unsigned short tile[64][66];
  int k0 = blockIdx.x * 64;
  int n0 = blockIdx.y * 64;
  int t = threadIdx.x;
#pragma unroll
  for (int i = 0; i < 4; i++) {
    int idx = t + i * 256;
    int r = idx >> 4, c4 = (idx & 15) << 2;
    float4 v = *reinterpret_cast<const float4*>(W1 + (size_t)(k0 + r) * HH + n0 + c4);
    tile[r][c4 + 0] = (unsigned short)f2bf(v.x);
    tile[r][c4 + 1] = (unsigned short)f2bf(v.y);
    tile[r][c4 + 2] = (unsigned short)f2bf(v.z);
    tile[r][c4 + 3] = (unsigned short)f2bf(v.w);
  }
  __syncthreads();
#pragma unroll
  for (int i = 0; i < 2; i++) {
    int idx = t + i * 256;
    int n = idx >> 3, k8 = (idx & 7) << 3;
    uint4 o;
    o.x = (unsigned)tile[k8 + 0][n] | ((unsigned)tile[k8 + 1][n] << 16);
    o.y = (unsigned)tile[k8 + 2][n] | ((unsigned)tile[k8 + 3][n] << 16);
    o.z = (unsigned)tile[k8 + 4][n] | ((unsigned)tile[k8 + 5][n] << 16);
    o.w = (unsigned)tile[k8 + 6][n] | ((unsigned)tile[k8 + 7][n] << 16);
    *reinterpret_cast<uint4*>(W1t + (size_t)(n0 + n) * H_ + k0 + k8) = o;
  }
}

// ---------------------------------------------------------------------------
// K1 (fast): gemm_v4 — 256x128 tile, BK=64, SINGLE-buffered 48 KiB LDS,
// 512 threads (8 waves, 4M x 2N), 2 blocks/CU (TLP hides the sync drain —
// the r1-proven mechanism) + 1.33x better FLOP/staged-byte than 128² tiles.
// Register budget: A-fragments read PER mi-group so liveness stays
// 64 acc + 32 bq + 8 af + addressing ~= 119 <= 128 (the 4-waves/EU cap) —
// no spills (round-6 version held 128 operand regs live and was capped).
// row&7 XOR swizzle (conflict-free ds_read_b128, counter-verified) applied
// via pre-swizzled global_load_lds source; m-major grid for XCD L2 locality.
// Fused relu(+b1)*W2 row-reduction epilogue -> s_pre.
// ---------------------------------------------------------------------------
__global__ __launch_bounds__(512, 4) void gemm_v4_kernel(
    const unsigned short* __restrict__ xb, const unsigned short* __restrict__ W1t,
    const float* __restrict__ b1, const float* __restrict__ W2,
    float* __restrict__ s_pre)
{
  __shared__ unsigned short As[256 * 64];   // 32 KiB, [row][k], granule-swizzled
  __shared__ unsigned short Bs[128 * 64];   // 16 KiB

  const int t    = threadIdx.x;
  const int m0   = blockIdx.x * 256;   // m-major: XCD = bx%8 -> A-panel locality
  const int n0   = blockIdx.y * 128;
  const int w    = t >> 6, lane = t & 63;
  const int wm   = w >> 1;             // 4 row-groups of 64
  const int wn   = w & 1;              // 2 col-groups of 64
  const int lcol = lane & 15, quad = lane >> 4;

  // staging: call j covers 64 rows (512 x 16B chunks). thread t -> row
  // j*64 + (t>>3), granule slot t&7; LDS granule s of row r holds global
  // k-chunk s^(r&7)  => source chunk = (t&7)^(srow&7)  (j*64 == 0 mod 8).
  const int srow = t >> 3;
  const int sq   = ((t & 7) ^ (srow & 7)) * 8;
  const unsigned short* aSb = xb  + (size_t)(m0 + srow) * H_ + sq;
  const unsigned short* bSb = W1t + (size_t)(n0 + srow) * H_ + sq;
  unsigned short* al = As + w * 512;        // + lane*16B by HW
  unsigned short* bl = Bs + w * 512;

  floatx4 acc[4][4] = {};

  for (int kk = 0; kk < H_; kk += 64) {
    __syncthreads();                        // prev iter's reads done (WAR)
#pragma unroll
    for (int j = 0; j < 4; ++j)
      gload_lds16(aSb + kk + (size_t)(64 * j) * H_, al + 4096 * j);
#pragma unroll
    for (int j = 0; j < 2; ++j)
      gload_lds16(bSb + kk + (size_t)(64 * j) * H_, bl + 4096 * j);
    __syncthreads();                        // vmcnt(0) drain: tile in LDS

    // B fragments for this wave's 64-col group: 8 reads, 32 VGPRs, reused
    // across all 4 mi-groups.
    bf16x8 bq[4][2];
#pragma unroll
    for (int ni = 0; ni < 4; ++ni) {
      int r = wn * 64 + ni * 16 + lcol;
#pragma unroll
      for (int kh = 0; kh < 2; ++kh)
        bq[ni][kh] = *reinterpret_cast<const bf16x8*>(
            Bs + r * 64 + (((kh * 4 + quad) ^ (r & 7)) * 8));
    }
    // A fragments read per mi-group (8 VGPRs live at a time).
#pragma unroll
    for (int mi = 0; mi < 4; ++mi) {
      int r = wm * 64 + mi * 16 + lcol;
      bf16x8 a0 = *reinterpret_cast<const bf16x8*>(
          As + r * 64 + (((quad) ^ (r & 7)) * 8));
      bf16x8 a1 = *reinterpret_cast<const bf16x8*>(
          As + r * 64 + (((4 + quad) ^ (r & 7)) * 8));
      __builtin_amdgcn_s_setprio(1);
#pragma unroll
      for (int ni = 0; ni < 4; ++ni) {
        acc[mi][ni] = __builtin_amdgcn_mfma_f32_16x16x32_bf16(a0, bq[ni][0], acc[mi][ni], 0, 0, 0);
        acc[mi][ni] = __builtin_amdgcn_mfma_f32_16x16x32_bf16(a1, bq[ni][1], acc[mi][ni], 0, 0, 0);
      }
      __builtin_amdgcn_s_setprio(0);
    }
  }

  // epilogue: relu(acc + b1[n]) * W2[n] summed over this block's 128 n-cols
  float rs[4][4] = {};
#pragma unroll
  for (int ni = 0; ni < 4; ++ni) {
    int n = n0 + wn * 64 + ni * 16 + lcol;        // C/D col = lane&15
    float b1v = b1[n], w2v = W2[n];
#pragma unroll
    for (int mi = 0; mi < 4; ++mi)
#pragma unroll
      for (int r = 0; r < 4; ++r)
        rs[mi][r] = fmaf(fmaxf(acc[mi][ni][r] + b1v, 0.f), w2v, rs[mi][r]);
  }
#pragma unroll
  for (int mi = 0; mi < 4; ++mi)
#pragma unroll
    for (int r = 0; r < 4; ++r) {
      float s = rs[mi][r];
      s += __shfl_xor(s, 1); s += __shfl_xor(s, 2);
      s += __shfl_xor(s, 4); s += __shfl_xor(s, 8);
      if (lcol == 0)
        atomicAdd(&s_pre[m0 + wm * 64 + mi * 16 + quad * 4 + r], s);
    }
}

// ---------------------------------------------------------------------------
// K1 (fallback, small ws): round-1 fused GEMM with in-loop conversion.
// ---------------------------------------------------------------------------
__global__ __launch_bounds__(256) void gemm_score_kernel(
    const float* __restrict__ x, const float* __restrict__ W1,
    const float* __restrict__ b1, const float* __restrict__ W2,
    float* __restrict__ s_pre)
{
  __shared__ unsigned short As[128][40];
  __shared__ unsigned short Bs[128][40];
  const int t    = threadIdx.x;
  const int n0   = blockIdx.x * 128;
  const int m0   = blockIdx.y * 128;
  const int wave = t >> 6, lane = t & 63;
  const int wr   = (wave >> 1) * 64;
  const int wc   = (wave & 1) * 64;
  const int lcol = lane & 15, quad = lane >> 4;
  floatx4 acc[4][4] = {};

  for (int kk = 0; kk < H_; kk += 32) {
    __syncthreads();
#pragma unroll
    for (int i = 0; i < 4; i++) {
      int idx = t + i * 256;
      int row = idx >> 3, k4 = (idx & 7) << 2;
      float4 v = *reinterpret_cast<const float4*>(x + (size_t)(m0 + row) * H_ + kk + k4);
      unsigned lo = f2bf(v.x) | (f2bf(v.y) << 16);
      unsigned hi = f2bf(v.z) | (f2bf(v.w) << 16);
      *reinterpret_cast<uint2*>(&As[row][k4]) = make_uint2(lo, hi);
    }
#pragma unroll
    for (int i = 0; i < 4; i++) {
      int idx = t + i * 256;
      int kr = idx >> 5, c4 = (idx & 31) << 2;
      float4 v = *reinterpret_cast<const float4*>(W1 + (size_t)(kk + kr) * HH + n0 + c4);
      Bs[c4 + 0][kr] = (unsigned short)f2bf(v.x);
      Bs[c4 + 1][kr] = (unsigned short)f2bf(v.y);
      Bs[c4 + 2][kr] = (unsigned short)f2bf(v.z);
      Bs[c4 + 3][kr] = (unsigned short)f2bf(v.w);
    }
    __syncthreads();
    bf16x8 af[4], bfr[4];
#pragma unroll
    for (int mt = 0; mt < 4; mt++)
      af[mt] = *reinterpret_cast<const bf16x8*>(&As[wr + mt * 16 + lcol][quad * 8]);
#pragma unroll
    for (int nt = 0; nt < 4; nt++)
      bfr[nt] = *reinterpret_cast<const bf16x8*>(&Bs[wc + nt * 16 + lcol][quad * 8]);
#pragma unroll
    for (int mt = 0; mt < 4; mt++)
#pragma unroll
      for (int nt = 0; nt < 4; nt++)
        acc[mt][nt] = __builtin_amdgcn_mfma_f32_16x16x32_bf16(af[mt], bfr[nt], acc[mt][nt], 0, 0, 0);
  }
  float rowsum[4][4];
#pragma unroll
  for (int mt = 0; mt < 4; mt++)
#pragma unroll
    for (int r = 0; r < 4; r++) rowsum[mt][r] = 0.f;
#pragma unroll
  for (int nt = 0; nt < 4; nt++) {
    int n = n0 + wc + nt * 16 + lcol;
    float b1v = b1[n], w2v = W2[n];
#pragma unroll
    for (int mt = 0; mt < 4; mt++)
#pragma unroll
      for (int r = 0; r < 4; r++) {
        float h = fmaxf(acc[mt][nt][r] + b1v, 0.f);
        rowsum[mt][r] = fmaf(h, w2v, rowsum[mt][r]);
      }
  }
#pragma unroll
  for (int mt = 0; mt < 4; mt++)
#pragma unroll
    for (int r = 0; r < 4; r++) {
      float s = rowsum[mt][r];
      s += __shfl_xor(s, 1); s += __shfl_xor(s, 2);
      s += __shfl_xor(s, 4); s += __shfl_xor(s, 8);
      if (lcol == 0)
        atomicAdd(&s_pre[m0 + wr + mt * 16 + quad * 4 + r], s);
    }
}

// ---------------------------------------------------------------------------
// K2+K3 fused: per-block (64 rows) event weights (wave 0) + block's partial
// of c from xb (bf16) into a PRIVATE slice (plain stores, no contention).
// ---------------------------------------------------------------------------
__global__ __launch_bounds__(256) void consolidate_partial_kernel(
    const unsigned short* __restrict__ xb, const float* __restrict__ s_pre,
    const float* __restrict__ imp, const float* __restrict__ b2,
    float* __restrict__ part, float* __restrict__ Z, float* __restrict__ cnt)
{
  __shared__ float wl[64];
  int t  = threadIdx.x;
  int r0 = blockIdx.x * 64;
  if (t < 64) {                                // wave 0 exactly
    float s   = s_pre[r0 + t] + b2[0];
    float sig = 1.f / (1.f + __expf(-s));
    bool  ev  = sig > 0.7f;
    float w   = ev ? __expf(imp[r0 + t]) : 0.f;
    wl[t] = w;
    float cw = ev ? 1.f : 0.f;
#pragma unroll
    for (int off = 32; off; off >>= 1) {
      w  += __shfl_down(w, off);
      cw += __shfl_down(cw, off);
    }
    if (t == 0) { atomicAdd(Z, w); atomicAdd(cnt, cw); }
  }
  __syncthreads();

  float a[8] = {0.f, 0.f, 0.f, 0.f, 0.f, 0.f, 0.f, 0.f};
  for (int r = 0; r < 64; ++r) {
    float w = wl[r];
    if (w != 0.f) {
      ushortx8 v = *reinterpret_cast<const ushortx8*>(
          xb + (size_t)(r0 + r) * H_ + t * 8);
#pragma unroll
      for (int e = 0; e < 8; ++e) a[e] = fmaf(w, bf2f(v[e]), a[e]);
    }
  }
  size_t base = (size_t)blockIdx.x * 2048 + t * 8;
#pragma unroll
  for (int e = 0; e < 8; ++e) part[base + e] = a[e];
}

// ---------------------------------------------------------------------------
// K3b: c[j] = sum over 256 block-partials (2 MB, plain reads, no atomics)
// ---------------------------------------------------------------------------
__global__ __launch_bounds__(256) void reduce_c_kernel(
    const float* __restrict__ part, float* __restrict__ c)
{
  int j = blockIdx.x * 256 + threadIdx.x;   // 8 blocks x 256 = 2048
  float s = 0.f;
#pragma unroll 8
  for (int b = 0; b < 256; ++b)
    s += part[(size_t)b * 2048 + j];
  c[j] = s;
}

// ---------------------------------------------------------------------------
// K2 (fallback path only)
// ---------------------------------------------------------------------------
__global__ __launch_bounds__(256) void score_kernel(
    const float* __restrict__ s_pre, const float* __restrict__ imp,
    const float* __restrict__ b2, float* __restrict__ wbuf,
    float* __restrict__ Z, float* __restrict__ cnt)
{
  int i = blockIdx.x * 256 + threadIdx.x;
  float s = s_pre[i] + b2[0];
  float sig = 1.f / (1.f + __expf(-s));
  bool ev = sig > 0.7f;
  float w = ev ? __expf(imp[i]) : 0.f;
  wbuf[i] = w;
  float cw = ev ? 1.f : 0.f;
#pragma unroll
  for (int off = 32; off; off >>= 1) {
    w  += __shfl_down(w, off);
    cw += __shfl_down(cw, off);
  }
  if ((threadIdx.x & 63) == 0) {
    atomicAdd(Z, w);
    atomicAdd(cnt, cw);
  }
}

// ---------------------------------------------------------------------------
// K3 (fallback path only): atomic consolidate from fp32 x.
// ---------------------------------------------------------------------------
__global__ __launch_bounds__(256) void consolidate_kernel(
    const float* __restrict__ x, const float* __restrict__ wbuf,
    float* __restrict__ c)
{
  int t = threadIdx.x;
  int r0 = blockIdx.x * 128;
  float a[8] = {0.f, 0.f, 0.f, 0.f, 0.f, 0.f, 0.f, 0.f};
  for (int r = 0; r < 128; r++) {
    float w = wbuf[r0 + r];
    if (w != 0.f) {
      const float4* xr = reinterpret_cast<const float4*>(x + (size_t)(r0 + r) * H_);
      float4 v0 = xr[t], v1 = xr[t + 256];
      a[0] = fmaf(w, v0.x, a[0]); a[1] = fmaf(w, v0.y, a[1]);
      a[2] = fmaf(w, v0.z, a[2]); a[3] = fmaf(w, v0.w, a[3]);
      a[4] = fmaf(w, v1.x, a[4]); a[5] = fmaf(w, v1.y, a[5]);
      a[6] = fmaf(w, v1.z, a[6]); a[7] = fmaf(w, v1.w, a[7]);
    }
  }
  int j0 = t * 4;
  atomicAdd(&c[j0 + 0], a[0]); atomicAdd(&c[j0 + 1], a[1]);
  atomicAdd(&c[j0 + 2], a[2]); atomicAdd(&c[j0 + 3], a[3]);
  atomicAdd(&c[1024 + j0 + 0], a[4]); atomicAdd(&c[1024 + j0 + 1], a[5]);
  atomicAdd(&c[1024 + j0 + 2], a[6]); atomicAdd(&c[1024 + j0 + 3], a[7]);
}

// ---------------------------------------------------------------------------
// K4: hr[n] += (c/Z) . W_r1[:,n]
// ---------------------------------------------------------------------------
__global__ __launch_bounds__(256) void r1_kernel(
    const float* __restrict__ c, const float* __restrict__ Z,
    const float* __restrict__ cnt, const float* __restrict__ Wr1,
    float* __restrict__ hr)
{
  __shared__ float cs[128];
  int n  = blockIdx.x * 256 + threadIdx.x;
  int k0 = blockIdx.y * 128;
  float inv = (cnt[0] > 0.5f) ? (1.f / Z[0]) : 0.f;
  if (threadIdx.x < 128) cs[threadIdx.x] = c[k0 + threadIdx.x] * inv;
  __syncthreads();
  float s = 0.f;
#pragma unroll 8
  for (int k = 0; k < 128; k++)
    s = fmaf(cs[k], Wr1[(size_t)(k0 + k) * HH + n], s);
  atomicAdd(&hr[n], s);
}

// ---------------------------------------------------------------------------
// K5: rt[n] += relu(hr + b_r1) . W_r2[:,n]
// ---------------------------------------------------------------------------
__global__ __launch_bounds__(256) void r2_kernel(
    const float* __restrict__ hr, const float* __restrict__ br1,
    const float* __restrict__ Wr2, float* __restrict__ rt)
{
  __shared__ float hs[128];
  int n  = blockIdx.x * 256 + threadIdx.x;
  int k0 = blockIdx.y * 128;
  if (threadIdx.x < 128)
    hs[threadIdx.x] = fmaxf(hr[k0 + threadIdx.x] + br1[k0 + threadIdx.x], 0.f);
  __syncthreads();
  float s = 0.f;
#pragma unroll 8
  for (int k = 0; k < 128; k++)
    s = fmaf(hs[k], Wr2[(size_t)(k0 + k) * H_ + n], s);
  atomicAdd(&rt[n], s);
}

// ---------------------------------------------------------------------------
// K6: add[j] = has_events ? sigmoid(rt[j] + b_r2[j]) : 0
// ---------------------------------------------------------------------------
__global__ __launch_bounds__(256) void finalize_kernel(
    const float* __restrict__ rt, const float* __restrict__ br2,
    const float* __restrict__ cnt, float* __restrict__ addv)
{
  int j = blockIdx.x * 256 + threadIdx.x;
  float v = 0.f;
  if (cnt[0] > 0.5f) v = 1.f / (1.f + expf(-(rt[j] + br2[j])));
  addv[j] = v;
}

// ---------------------------------------------------------------------------
// K7: out = x + add (broadcast over rows). Grid-stride, addv loop-invariant.
// ---------------------------------------------------------------------------
__global__ __launch_bounds__(256) void out_kernel(
    const float* __restrict__ x, const float* __restrict__ addv,
    float* __restrict__ out)
{
  size_t base = (size_t)blockIdx.x * 256 + threadIdx.x;   // float4 index
  float4 a = reinterpret_cast<const float4*>(addv)[(int)(base & 511)];
#pragma unroll
  for (int it = 0; it < 16; ++it) {
    size_t i = base + (size_t)it * 524288u;   // stride % 512 == 0 -> same addv
    float4 v = reinterpret_cast<const float4*>(x)[i];
    v.x += a.x; v.y += a.y; v.z += a.z; v.w += a.w;
    reinterpret_cast<float4*>(out)[i] = v;
  }
}

// ---------------------------------------------------------------------------
extern "C" void kernel_launch(void* const* d_in, const int* in_sizes, int n_in,
                              void* d_out, int out_size, void* d_ws, size_t ws_size,
                              hipStream_t stream)
{
  (void)in_sizes; (void)n_in; (void)out_size;
  const float* x   = (const float*)d_in[0];
  const float* imp = (const float*)d_in[1];
  const float* We1 = (const float*)d_in[2];
  const float* be1 = (const float*)d_in[3];
  const float* We2 = (const float*)d_in[4];
  const float* be2 = (const float*)d_in[5];
  const float* Wr1 = (const float*)d_in[6];
  const float* br1 = (const float*)d_in[7];
  const float* Wr2 = (const float*)d_in[8];
  const float* br2 = (const float*)d_in[9];
  float* out = (float*)d_out;

  float* ws    = (float*)d_ws;
  float* s_pre = ws;            // 16384
  float* c     = ws + 16384;    // 2048
  float* hr    = ws + 18432;    // 1024
  float* rt    = ws + 19456;    // 2048
  float* Z     = ws + 21504;    // 1
  float* cnt   = ws + 21505;    // 1
  float* wbuf  = ws + 21760;    // 16384 (fallback path only)
  float* addv  = ws + 38144;    // 2048  (fully written, no init)

  const size_t scal_bytes = 49152 * sizeof(float);             // 196608 B
  const size_t xb_bytes   = (size_t)NROWS * H_ * 2;            // 67.1 MB
  const size_t w1t_bytes  = (size_t)HH * H_ * 2;               // 4.2 MB
  unsigned short* xb  = (unsigned short*)((char*)d_ws + scal_bytes);
  unsigned short* W1t = (unsigned short*)((char*)d_ws + scal_bytes + xb_bytes);
  // W1t is dead after the gemm -> reuse its storage for the 256x2048 partials
  float* part = (float*)W1t;
  const bool fast = ws_size >= scal_bytes + xb_bytes + w1t_bytes;

  hipMemsetAsync(d_ws, 0, 21506 * sizeof(float), stream);

  if (fast) {
    convert_x_kernel<<<2048, 256, 0, stream>>>(x, xb);
    transpose_w1_kernel<<<dim3(32, 16), 256, 0, stream>>>(We1, W1t);
    gemm_v4_kernel<<<dim3(64, 8), 512, 0, stream>>>(xb, W1t, be1, We2, s_pre);
    consolidate_partial_kernel<<<256, 256, 0, stream>>>(xb, s_pre, imp, be2, part, Z, cnt);
    reduce_c_kernel<<<8, 256, 0, stream>>>(part, c);
  } else {
    gemm_score_kernel<<<dim3(8, 128), 256, 0, stream>>>(x, We1, be1, We2, s_pre);
    score_kernel<<<64, 256, 0, stream>>>(s_pre, imp, be2, wbuf, Z, cnt);
    consolidate_kernel<<<128, 256, 0, stream>>>(x, wbuf, c);
  }
  r1_kernel<<<dim3(4, 16), 256, 0, stream>>>(c, Z, cnt, Wr1, hr);
  r2_kernel<<<dim3(8, 8), 256, 0, stream>>>(hr, br1, Wr2, rt);
  finalize_kernel<<<8, 256, 0, stream>>>(rt, br2, cnt, addv);
  out_kernel<<<2048, 256, 0, stream>>>(x, addv, out);
}